// Round 1
// 1196.394 us; speedup vs baseline: 1.0624x; 1.0624x over previous
//
#include <hip/hip_runtime.h>
#include <hip/hip_bf16.h>

typedef __hip_bfloat16 bf16;
typedef __attribute__((ext_vector_type(8))) short short8;
typedef __attribute__((ext_vector_type(4))) float f32x4;

#define MAXN 0.996f      // (1 - 4e-3)/sqrt(c), c=1
#define MINN 1e-15f

__device__ __forceinline__ float b2f(short s) {
    union { unsigned u; float f; } c; c.u = ((unsigned)(unsigned short)s) << 16; return c.f;
}
__device__ __forceinline__ short f2b(float f) {   // RNE bf16
    union { float f; unsigned u; } c; c.f = f;
    unsigned r = c.u + 0x7FFF + ((c.u >> 16) & 1);
    return (short)(r >> 16);
}
__device__ __forceinline__ float cv(short v) { return b2f(v); }
__device__ __forceinline__ float cv(float v) { return v; }
__device__ __forceinline__ short tb(short v) { return v; }
__device__ __forceinline__ short tb(float v) { return f2b(v); }
__device__ __forceinline__ short8 ld8(const short* p) { return *(const short8*)p; }
__device__ __forceinline__ short8 ld8(const float* p) {
    float4 a = *(const float4*)p, b = *(const float4*)(p + 4);
    short8 r;
    r[0] = f2b(a.x); r[1] = f2b(a.y); r[2] = f2b(a.z); r[3] = f2b(a.w);
    r[4] = f2b(b.x); r[5] = f2b(b.y); r[6] = f2b(b.z); r[7] = f2b(b.w);
    return r;
}
__device__ __forceinline__ void ldf8(const short* p, float* f) {
    short8 v = *(const short8*)p;
#pragma unroll
    for (int j = 0; j < 8; ++j) f[j] = b2f(v[j]);
}
__device__ __forceinline__ void ldf8(const float* p, float* f) {
    float4 a = *(const float4*)p, b = *(const float4*)(p + 4);
    f[0] = a.x; f[1] = a.y; f[2] = a.z; f[3] = a.w;
    f[4] = b.x; f[5] = b.y; f[6] = b.z; f[7] = b.w;
}
__device__ __forceinline__ void st(short* p, float v) { *p = f2b(v); }
__device__ __forceinline__ void st(float* p, float v) { *p = v; }

__device__ __forceinline__ float wave_sum(float v) {
#pragma unroll
    for (int m = 1; m < 64; m <<= 1) v += __shfl_xor(v, m);
    return v;
}
__device__ __forceinline__ float red16(float v) {
#pragma unroll
    for (int m = 1; m < 16; m <<= 1) v += __shfl_xor(v, m);
    return v;
}
__device__ __forceinline__ float artanh_(float x) {
    x = fminf(fmaxf(x, -1.f + 1e-7f), 1.f - 1e-7f);
    return 0.5f * (log1pf(x) - log1pf(-x));
}
__device__ __forceinline__ float sigmoidf_(float x) { return 1.f / (1.f + expf(-x)); }

// flag: 0 = storage is bf16, 1 = storage is f32
template <typename T> __device__ __forceinline__ bool skip(const int* flag) {
    return *flag != (int)(sizeof(T) == 4);
}

// ---------------- dtype detector ----------------
__global__ void k_detect(const void* hid, int* flag) {
    const short* p = (const short*)hid;
    int t = threadIdx.x;
    int bad = 0;
    for (int i = t; i < 4096; i += 256) {
        unsigned u = (unsigned)(unsigned short)p[i];
        unsigned ex = (u >> 7) & 0xFF;
        if (ex >= 128) bad = 1;   // |v| >= 2 or NaN/Inf -> cannot be in-ball bf16 data
    }
    __shared__ int s;
    if (t == 0) s = 0;
    __syncthreads();
    if (bad) atomicOr(&s, 1);
    __syncthreads();
    if (t == 0) *flag = s;
}

// ---------------- prep ----------------
template <typename T>
__global__ void k_prep(const T* __restrict__ b1, const T* __restrict__ b2,
                       const T* __restrict__ bl, const T* __restrict__ bih,
                       const T* __restrict__ bhh, const T* __restrict__ Q,
                       const T* __restrict__ ratt, const T* __restrict__ Wih,
                       const T* __restrict__ Whh,
                       float* hb1, float* y2a, float* hb2, float* y2b,
                       float* blf, float* bs256, float* ratf,
                       short* QT, short* Wc, const int* flag) {
    if (skip<T>(flag)) return;
    __shared__ float sb[256];
    int t = threadIdx.x;
    float v1 = (t < 128) ? cv(b1[t]) : 0.f;
    sb[t] = v1 * v1; __syncthreads();
    for (int d = 128; d > 0; d >>= 1) { if (t < d) sb[t] += sb[t + d]; __syncthreads(); }
    float n2a = sb[0]; __syncthreads();
    {
        float un = fmaxf(sqrtf(n2a), MINN);
        float e = tanhf(un), tt = e / un;
        float s = (e > MAXN) ? MAXN / e : 1.f;
        if (t < 128) hb1[t] = s * tt * v1;
        if (t == 0) { float hn = s * e; y2a[0] = hn * hn; }
    }
    float v2 = (t < 64) ? cv(b2[t]) : 0.f;
    sb[t] = v2 * v2; __syncthreads();
    for (int d = 128; d > 0; d >>= 1) { if (t < d) sb[t] += sb[t + d]; __syncthreads(); }
    float n2b = sb[0]; __syncthreads();
    {
        float un = fmaxf(sqrtf(n2b), MINN);
        float e = tanhf(un), tt = e / un;
        float s = (e > MAXN) ? MAXN / e : 1.f;
        if (t < 64) hb2[t] = s * tt * v2;
        if (t == 0) { float hn = s * e; y2b[0] = hn * hn; }
    }
    for (int i = t; i < 64; i += 256) {
        blf[i] = cv(bl[i]);
        ratf[i] = cv(ratt[i]);
    }
    {
        float v = (t < 192) ? (cv(bih[t]) + cv(bhh[t])) : cv(bhh[t - 64]);
        bs256[t] = v;
    }
    for (int i = t; i < 4096; i += 256) { int k = i >> 6, n = i & 63; QT[n * 64 + k] = tb(Q[k * 64 + n]); }
    for (int i = t; i < 256 * 128; i += 256) {
        int d = i >> 7, j = i & 127;
        short v;
        if (d < 192) v = (j < 64) ? tb(Wih[d * 64 + j]) : tb(Whh[d * 64 + (j - 64)]);
        else         v = (j < 64) ? (short)0 : tb(Whh[(d - 64) * 64 + (j - 64)]);
        Wc[i] = v;
    }
}

// ---------------- CSR ----------------
__global__ void k_zero(int* __restrict__ a, int* __restrict__ b, int N) {
    int i = blockIdx.x * blockDim.x + threadIdx.x;
    if (i < N) { a[i] = 0; b[i] = 0; }
}
__global__ void k_count(const int* __restrict__ src, int E, int* __restrict__ cnt) {
    int i = blockIdx.x * blockDim.x + threadIdx.x;
    if (i < E) atomicAdd(&cnt[src[i]], 1);
}
__global__ __launch_bounds__(1024) void k_scan(const int* __restrict__ cnt, int* __restrict__ rowptr, int N) {
    __shared__ int part[1024];
    int t = threadIdx.x;
    int Cn = (N + 1023) / 1024;
    int lo = t * Cn, hi = min(lo + Cn, N);
    int s = 0;
    for (int i = lo; i < hi; ++i) s += cnt[i];
    part[t] = s; __syncthreads();
    for (int d = 1; d < 1024; d <<= 1) {
        int v = (t >= d) ? part[t - d] : 0; __syncthreads();
        part[t] += v; __syncthreads();
    }
    int run = (t == 0) ? 0 : part[t - 1];
    for (int i = lo; i < hi; ++i) { rowptr[i] = run; run += cnt[i]; }
    if (hi == N && lo < N) rowptr[N] = run;
}
__global__ void k_dis(const int* __restrict__ cnt, float* __restrict__ dis, int N) {
    int i = blockIdx.x * blockDim.x + threadIdx.x;
    if (i < N) dis[i] = 1.f / sqrtf((float)(cnt[i] + 1));
}
__global__ void k_fill(const int* __restrict__ src, const int* __restrict__ dst, int E,
                       const int* __restrict__ rowptr, int* __restrict__ fill, int* __restrict__ ecol) {
    int i = blockIdx.x * blockDim.x + threadIdx.x;
    if (i < E) {
        int s = src[i];
        int p = rowptr[s] + atomicAdd(&fill[s], 1);
        ecol[p] = dst[i];
    }
}

// --------- attention E: fused logmap0 -> (hlog@Q) -> tanh -> @r_att ------
// Also caches the per-row logmap0 scale lt = artanh(|p|)/|p| into Lt so the
// combine kernel (k_att_h) doesn't have to recompute norm+artanh per row.
template <typename T>
__global__ __launch_bounds__(256) void k_att_e(const T* __restrict__ hid,
                                               const short* __restrict__ QT,
                                               const float* __restrict__ ratf,
                                               float* __restrict__ Eo,
                                               float* __restrict__ Lt,
                                               int rows, const int* flag) {
    if (skip<T>(flag)) return;
    int wid = threadIdx.x >> 6, lane = threadIdx.x & 63;
    int row0 = blockIdx.x * 64 + wid * 16;
    if (row0 >= rows) return;
    int l15 = lane & 15, quad = lane >> 4;
    const T* Hrow = hid + (size_t)(row0 + l15) * 64 + quad * 8;
    float f0[8], f1[8];
    ldf8(Hrow, f0); ldf8(Hrow + 32, f1);
    float sq = 0.f;
#pragma unroll
    for (int j = 0; j < 8; ++j) sq += f0[j] * f0[j] + f1[j] * f1[j];
    sq += __shfl_xor(sq, 16); sq += __shfl_xor(sq, 32);
    float pn = fmaxf(sqrtf(sq), MINN);
    float lt = artanh_(pn) / pn;
    if (quad == 0) Lt[row0 + l15] = lt;   // cache for k_att_h
    short8 s0, s1;
#pragma unroll
    for (int j = 0; j < 8; ++j) { s0[j] = f2b(lt * f0[j]); s1[j] = f2b(lt * f1[j]); }
    f32x4 acc[4];
#pragma unroll
    for (int nt = 0; nt < 4; ++nt) acc[nt] = (f32x4){0.f, 0.f, 0.f, 0.f};
#pragma unroll
    for (int nt = 0; nt < 4; ++nt) {
        short8 b0 = *(const short8*)(QT + (size_t)(nt * 16 + l15) * 64 + quad * 8);
        short8 b1 = *(const short8*)(QT + (size_t)(nt * 16 + l15) * 64 + 32 + quad * 8);
        acc[nt] = __builtin_amdgcn_mfma_f32_16x16x32_bf16(s0, b0, acc[nt], 0, 0, 0);
        acc[nt] = __builtin_amdgcn_mfma_f32_16x16x32_bf16(s1, b1, acc[nt], 0, 0, 0);
    }
#pragma unroll
    for (int r = 0; r < 4; ++r) {
        float s = 0.f;
#pragma unroll
        for (int nt = 0; nt < 4; ++nt) s += tanhf(acc[nt][r]) * ratf[nt * 16 + l15];
        s = red16(s);
        if (l15 == 0) Eo[row0 + quad * 4 + r] = s;
    }
}

// --------- attention combine: softmax over window, h = mean(a*hlog) -----
// VALU-light version: reuses Lt (logmap0 scale) computed in k_att_e instead
// of re-deriving norm+artanh per (node, window). Memory-bound streaming.
template <typename T>
__global__ __launch_bounds__(256) void k_att_h(const float* __restrict__ Eb,
                                               const float* __restrict__ Lt,
                                               const T* __restrict__ hid,
                                               bf16* __restrict__ Hb, int N, int win, const int* flag) {
    if (skip<T>(flag)) return;
    int wid = threadIdx.x >> 6, lane = threadIdx.x & 63;
    int i = blockIdx.x * 4 + wid;
    if (i >= N) return;
    float hl[8], ev[8];
    float m = -1e30f;
    for (int w = 0; w < win; ++w) {
        float p = cv(hid[((size_t)w * N + i) * 64 + lane]);
        hl[w] = Lt[(size_t)w * N + i] * p;
        ev[w] = Eb[(size_t)w * N + i];
        m = fmaxf(m, ev[w]);
    }
    float s = 0.f;
    for (int w = 0; w < win; ++w) { ev[w] = expf(ev[w] - m); s += ev[w]; }
    float h = 0.f;
    for (int w = 0; w < win; ++w) h += ev[w] * hl[w];
    ((short*)Hb)[(size_t)i * 64 + lane] = f2b(h / (s * (float)win));
}

// --------- initial linear + expmap0/proj + concat hidden + proj128 ------
template <typename T>
__global__ __launch_bounds__(256) void k_lin0(const T* __restrict__ feat, const T* __restrict__ Wl,
                                              const float* __restrict__ blf, const T* __restrict__ hid,
                                              int win, float* __restrict__ xnorm,
                                              bf16* __restrict__ outA, int N, const int* flag) {
    if (skip<T>(flag)) return;
    int wid = threadIdx.x >> 6, lane = threadIdx.x & 63;
    int row0 = blockIdx.x * 64 + wid * 16;
    if (row0 >= N) return;
    int l15 = lane & 15, quad = lane >> 4;
    f32x4 acc[4];
#pragma unroll
    for (int nt = 0; nt < 4; ++nt) acc[nt] = (f32x4){0.f, 0.f, 0.f, 0.f};
    const T* Arow = feat + (size_t)(row0 + l15) * 128 + quad * 8;
    for (int k0 = 0; k0 < 128; k0 += 32) {
        short8 a = ld8(Arow + k0);
#pragma unroll
        for (int nt = 0; nt < 4; ++nt) {
            short8 b = ld8(Wl + (size_t)(nt * 16 + l15) * 128 + k0 + quad * 8);
            acc[nt] = __builtin_amdgcn_mfma_f32_16x16x32_bf16(a, b, acc[nt], 0, 0, 0);
        }
    }
    float bv[4];
#pragma unroll
    for (int nt = 0; nt < 4; ++nt) bv[nt] = blf[nt * 16 + l15];
#pragma unroll
    for (int r = 0; r < 4; ++r) {
        int row = row0 + quad * 4 + r;
        float g[4], u2 = 0.f;
#pragma unroll
        for (int nt = 0; nt < 4; ++nt) { g[nt] = acc[nt][r] + bv[nt]; u2 += g[nt] * g[nt]; }
        u2 = red16(u2);
        float un = fmaxf(sqrtf(u2), MINN);
        float e = tanhf(un), t = e / un;
        float s1 = (e > MAXN) ? MAXN / e : 1.f;
        float x0n = s1 * e;
        float hv[4], h2 = 0.f;
#pragma unroll
        for (int nt = 0; nt < 4; ++nt) {
            hv[nt] = cv(hid[((size_t)(win - 1) * N + row) * 64 + nt * 16 + l15]);
            h2 += hv[nt] * hv[nt];
        }
        h2 = red16(h2);
        float n128 = sqrtf(x0n * x0n + h2);
        float s2 = (n128 > MAXN) ? MAXN / n128 : 1.f;
#pragma unroll
        for (int nt = 0; nt < 4; ++nt) {
            ((short*)outA)[(size_t)row * 128 + nt * 16 + l15] = f2b(s2 * s1 * t * g[nt]);
            ((short*)outA)[(size_t)row * 128 + 64 + nt * 16 + l15] = f2b(s2 * hv[nt]);
        }
        if (l15 == 0) xnorm[row] = fmaxf(fminf(n128, MAXN), MINN);
    }
}

// ------- conv linear: GEMM fused with matvec->proj->madd(hb)->proj->logmap0 ----
template <int DOUT, typename T>
__global__ __launch_bounds__(256) void k_conv_lin(const bf16* __restrict__ in, const T* __restrict__ W,
                                                  const float* __restrict__ hb, const float* __restrict__ y2p,
                                                  const float* __restrict__ xnorm,
                                                  bf16* __restrict__ out, int N, const int* flag) {
    if (skip<T>(flag)) return;
    constexpr int NT = DOUT / 16;
    int wid = threadIdx.x >> 6, lane = threadIdx.x & 63;
    int row0 = blockIdx.x * 64 + wid * 16;
    if (row0 >= N) return;
    int l15 = lane & 15, quad = lane >> 4;
    f32x4 acc[NT];
#pragma unroll
    for (int nt = 0; nt < NT; ++nt) acc[nt] = (f32x4){0.f, 0.f, 0.f, 0.f};
    const short* Arow = (const short*)in + (size_t)(row0 + l15) * 128 + quad * 8;
    for (int k0 = 0; k0 < 128; k0 += 32) {
        short8 a = *(const short8*)(Arow + k0);
#pragma unroll
        for (int nt = 0; nt < NT; ++nt) {
            short8 b = ld8(W + (size_t)(nt * 16 + l15) * 128 + k0 + quad * 8);
            acc[nt] = __builtin_amdgcn_mfma_f32_16x16x32_bf16(a, b, acc[nt], 0, 0, 0);
        }
    }
    float y2 = y2p[0];
    float hbv[NT];
#pragma unroll
    for (int nt = 0; nt < NT; ++nt) hbv[nt] = hb[nt * 16 + l15];
#pragma unroll
    for (int r = 0; r < 4; ++r) {
        int row = row0 + quad * 4 + r;
        float mx[NT], m2 = 0.f;
#pragma unroll
        for (int nt = 0; nt < NT; ++nt) { mx[nt] = acc[nt][r]; m2 += mx[nt] * mx[nt]; }
        m2 = red16(m2);
        float mxn = fmaxf(sqrtf(m2), MINN);
        float xn = xnorm[row];
        float at = artanh_(xn);
        float f = (m2 == 0.f) ? 0.f : tanhf(mxn / xn * at) / mxn;
        float rn = f * mxn;
        float s1 = (rn > MAXN) ? MAXN / rn : 1.f;
        float a_ = s1 * f, mvn = s1 * rn;
        float x2 = mvn * mvn;
        float xy = 0.f;
#pragma unroll
        for (int nt = 0; nt < NT; ++nt) xy += (a_ * mx[nt]) * hbv[nt];
        xy = red16(xy);
        float co = 1.f + 2.f * xy + y2, cx = 1.f - x2;
        float den = fmaxf(1.f + 2.f * xy + x2 * y2, MINN);
        float o[NT], on2 = 0.f;
#pragma unroll
        for (int nt = 0; nt < NT; ++nt) { o[nt] = (co * a_ * mx[nt] + cx * hbv[nt]) / den; on2 += o[nt] * o[nt]; }
        on2 = red16(on2);
        float on = sqrtf(on2);
        float s3 = (on > MAXN) ? MAXN / on : 1.f;
        float hn = fmaxf(s3 * on, MINN);
        float lt = artanh_(hn) / hn;
#pragma unroll
        for (int nt = 0; nt < NT; ++nt)
            ((short*)out)[(size_t)row * 128 + nt * 16 + l15] = f2b(lt * s3 * o[nt]);
    }
}

// --------- aggregation + expmap0/proj + HypAct [+final logmap0] ----------
template <int DPL, bool FINAL>
__global__ __launch_bounds__(256) void k_agg(const bf16* __restrict__ xt, const int* __restrict__ rowptr,
                                             const int* __restrict__ ecol, const float* __restrict__ dis,
                                             bf16* __restrict__ out, float* __restrict__ xnorm,
                                             const bf16* __restrict__ Hb, int N) {
    int wid = threadIdx.x >> 6, lane = threadIdx.x & 63;
    int i = blockIdx.x * 4 + wid;
    if (i >= N) return;
    const short* xs = (const short*)xt;
    float di = dis[i];
    float w0 = di * di;
    float a0 = w0 * b2f(xs[(size_t)i * 128 + lane]);
    float a1 = 0.f;
    if (DPL == 2) a1 = w0 * b2f(xs[(size_t)i * 128 + 64 + lane]);
    int e0 = rowptr[i], e1 = rowptr[i + 1];
    for (int j = e0; j < e1; ++j) {
        int c = ecol[j];
        float w = di * dis[c];
        a0 += w * b2f(xs[(size_t)c * 128 + lane]);
        if (DPL == 2) a1 += w * b2f(xs[(size_t)c * 128 + 64 + lane]);
    }
    float an = fmaxf(sqrtf(wave_sum(a0 * a0 + a1 * a1)), MINN);
    float e1t = tanhf(an), t1 = e1t / an;
    float s1 = (e1t > MAXN) ? MAXN / e1t : 1.f;
    float hn = fmaxf(s1 * e1t, MINN);
    float lt = artanh_(hn) / hn;
    float sht = s1 * t1 * lt;
    float v0 = sht * a0; v0 = (v0 >= 0.f) ? v0 : 0.01f * v0;
    float v1 = sht * a1; v1 = (v1 >= 0.f) ? v1 : 0.01f * v1;
    float tn = fmaxf(sqrtf(wave_sum(v0 * v0 + v1 * v1)), MINN);
    float e2 = tanhf(tn), t2 = e2 / tn;
    float s2 = (e2 > MAXN) ? MAXN / e2 : 1.f;
    float sc = s2 * t2;
    float r0 = sc * v0, r1 = sc * v1;
    if (FINAL) {
        float xnf = fmaxf(fminf(s2 * e2, MAXN), MINN);
        float lt2 = artanh_(xnf) / xnf;
        r0 *= lt2; r1 *= lt2;
    }
    short* os = (short*)out;
    os[(size_t)i * 128 + lane] = f2b(r0);
    if (DPL == 2) {
        os[(size_t)i * 128 + 64 + lane] = f2b(r1);
        if (lane == 0 && xnorm) xnorm[i] = fmaxf(fminf(e2, MAXN), MINN);
    } else {
        os[(size_t)i * 128 + 64 + lane] = ((const short*)Hb)[(size_t)i * 64 + lane];
    }
}

// --------- GRU fused + expmap0/proj -> out (templated on OUT dtype) -----
template <typename OT>
__global__ __launch_bounds__(256) void k_gru_f(const bf16* __restrict__ cat, const short* __restrict__ Wc,
                                               const float* __restrict__ bs, const bf16* __restrict__ Hb,
                                               OT* __restrict__ out, int N, const int* flag) {
    if (skip<OT>(flag)) return;
    int wid = threadIdx.x >> 6, lane = threadIdx.x & 63;
    int row0 = blockIdx.x * 64 + wid * 16;
    if (row0 >= N) return;
    int l15 = lane & 15, quad = lane >> 4;
    f32x4 acc[16];
#pragma unroll
    for (int nt = 0; nt < 16; ++nt) acc[nt] = (f32x4){0.f, 0.f, 0.f, 0.f};
    const short* Arow = (const short*)cat + (size_t)(row0 + l15) * 128 + quad * 8;
    for (int k0 = 0; k0 < 128; k0 += 32) {
        short8 a = *(const short8*)(Arow + k0);
#pragma unroll
        for (int nt = 0; nt < 16; ++nt) {
            short8 b = *(const short8*)(Wc + (size_t)(nt * 16 + l15) * 128 + k0 + quad * 8);
            acc[nt] = __builtin_amdgcn_mfma_f32_16x16x32_bf16(a, b, acc[nt], 0, 0, 0);
        }
    }
#pragma unroll
    for (int r = 0; r < 4; ++r) {
        int row = row0 + quad * 4 + r;
        float zv[4], z2 = 0.f;
#pragma unroll
        for (int nt = 0; nt < 4; ++nt) {
            int c = nt * 16 + l15;
            float gr = acc[nt][r] + bs[c];
            float gz = acc[nt + 4][r] + bs[c + 64];
            float gn = acc[nt + 8][r] + bs[c + 128];
            float hn = acc[nt + 12][r] + bs[c + 192];
            float hv = b2f(((const short*)Hb)[(size_t)row * 64 + c]);
            float rr = sigmoidf_(gr), zz = sigmoidf_(gz);
            float nn = tanhf(gn + (rr - 1.f) * hn);
            zv[nt] = (1.f - zz) * nn + zz * hv;
            z2 += zv[nt] * zv[nt];
        }
        z2 = red16(z2);
        float un = fmaxf(sqrtf(z2), MINN);
        float e = tanhf(un), t = e / un;
        float s = (e > MAXN) ? MAXN / e : 1.f;
#pragma unroll
        for (int nt = 0; nt < 4; ++nt)
            st(&out[(size_t)row * 64 + nt * 16 + l15], s * t * zv[nt]);
    }
}

extern "C" void kernel_launch(void* const* d_in, const int* in_sizes, int n_in,
                              void* d_out, int out_size, void* d_ws, size_t ws_size,
                              hipStream_t stream) {
    const int E = in_sizes[0] / 2;
    const int N = in_sizes[1] / 128;
    int win = in_sizes[14] / (N * 64); if (win > 8) win = 8;

    char* wp = (char*)d_ws;
    auto alloc = [&](size_t bytes) -> void* {
        void* p = (void*)wp;
        wp += (bytes + 255) & ~(size_t)255;
        return p;
    };
    bf16* bufA = (bf16*)alloc((size_t)N * 128 * 2);
    bf16* bufB = (bf16*)alloc((size_t)N * 128 * 2);
    bf16* Hbf  = (bf16*)alloc((size_t)N * 64 * 2);
    float* Ebuf = (float*)alloc((size_t)win * N * 4);
    float* Ltb  = (float*)alloc((size_t)win * N * 4);
    float* xnorm = (float*)alloc((size_t)N * 4);
    int* cnt = (int*)alloc((size_t)N * 4);
    int* fillc = (int*)alloc((size_t)N * 4);
    int* rowptr = (int*)alloc((size_t)(N + 1) * 4);
    float* dis = (float*)alloc((size_t)N * 4);
    int* ecol = (int*)alloc((size_t)E * 4);
    float* hb1 = (float*)alloc(128 * 4);
    float* y2a = (float*)alloc(256);
    float* hb2 = (float*)alloc(64 * 4);
    float* y2b = (float*)alloc(256);
    float* blf = (float*)alloc(64 * 4);
    float* bs256 = (float*)alloc(256 * 4);
    float* ratf = (float*)alloc(64 * 4);
    short* QT = (short*)alloc(4096 * 2);
    short* Wc = (short*)alloc((size_t)256 * 128 * 2);
    int* flag = (int*)alloc(256);
    (void)ws_size; (void)out_size; (void)n_in;

    const int* ei = (const int*)d_in[0];

    k_detect<<<1, 256, 0, stream>>>(d_in[14], flag);

    // prep (both dtype variants; non-matching exits immediately)
#define P(T) (const T*)d_in
    k_prep<short><<<1, 256, 0, stream>>>(P(short)[5], P(short)[7], P(short)[3], P(short)[12], P(short)[13],
                                         P(short)[8], P(short)[9], P(short)[10], P(short)[11],
                                         hb1, y2a, hb2, y2b, blf, bs256, ratf, QT, Wc, flag);
    k_prep<float><<<1, 256, 0, stream>>>(P(float)[5], P(float)[7], P(float)[3], P(float)[12], P(float)[13],
                                         P(float)[8], P(float)[9], P(float)[10], P(float)[11],
                                         hb1, y2a, hb2, y2b, blf, bs256, ratf, QT, Wc, flag);
    // CSR build (dtype-free)
    k_zero<<<(N + 255) / 256, 256, 0, stream>>>(cnt, fillc, N);
    k_count<<<(E + 255) / 256, 256, 0, stream>>>(ei, E, cnt);
    k_scan<<<1, 1024, 0, stream>>>(cnt, rowptr, N);
    k_dis<<<(N + 255) / 256, 256, 0, stream>>>(cnt, dis, N);
    k_fill<<<(E + 255) / 256, 256, 0, stream>>>(ei, ei + E, E, rowptr, fillc, ecol);
    // HTA window attention
    int rowsHL = win * N;
    k_att_e<short><<<(rowsHL + 63) / 64, 256, 0, stream>>>(P(short)[14], QT, ratf, Ebuf, Ltb, rowsHL, flag);
    k_att_e<float><<<(rowsHL + 63) / 64, 256, 0, stream>>>(P(float)[14], QT, ratf, Ebuf, Ltb, rowsHL, flag);
    k_att_h<short><<<(N + 3) / 4, 256, 0, stream>>>(Ebuf, Ltb, P(short)[14], Hbf, N, win, flag);
    k_att_h<float><<<(N + 3) / 4, 256, 0, stream>>>(Ebuf, Ltb, P(float)[14], Hbf, N, win, flag);
    // initial linear + toHyperX + concat
    k_lin0<short><<<(N + 63) / 64, 256, 0, stream>>>(P(short)[1], P(short)[2], blf, P(short)[14], win, xnorm, bufA, N, flag);
    k_lin0<float><<<(N + 63) / 64, 256, 0, stream>>>(P(float)[1], P(float)[2], blf, P(float)[14], win, xnorm, bufA, N, flag);
    // conv1
    k_conv_lin<128, short><<<(N + 63) / 64, 256, 0, stream>>>(bufA, P(short)[4], hb1, y2a, xnorm, bufA, N, flag);
    k_conv_lin<128, float><<<(N + 63) / 64, 256, 0, stream>>>(bufA, P(float)[4], hb1, y2a, xnorm, bufA, N, flag);
    k_agg<2, false><<<(N + 3) / 4, 256, 0, stream>>>(bufA, rowptr, ecol, dis, bufB, xnorm, nullptr, N);
    // conv2
    k_conv_lin<64, short><<<(N + 63) / 64, 256, 0, stream>>>(bufB, P(short)[6], hb2, y2b, xnorm, bufB, N, flag);
    k_conv_lin<64, float><<<(N + 63) / 64, 256, 0, stream>>>(bufB, P(float)[6], hb2, y2b, xnorm, bufB, N, flag);
    k_agg<1, true><<<(N + 3) / 4, 256, 0, stream>>>(bufB, rowptr, ecol, dis, bufA, nullptr, Hbf, N);
    // GRU fused + toHyperX -> out (output dtype = detected input dtype)
    k_gru_f<short><<<(N + 63) / 64, 256, 0, stream>>>(bufA, Wc, bs256, Hbf, (short*)d_out, N, flag);
    k_gru_f<float><<<(N + 63) / 64, 256, 0, stream>>>(bufA, Wc, bs256, Hbf, (float*)d_out, N, flag);
#undef P
}

// Round 2
// 965.967 us; speedup vs baseline: 1.3159x; 1.2385x over previous
//
#include <hip/hip_runtime.h>
#include <hip/hip_bf16.h>

typedef __hip_bfloat16 bf16;
typedef __attribute__((ext_vector_type(8))) short short8;
typedef __attribute__((ext_vector_type(4))) float f32x4;

#define MAXN 0.996f      // (1 - 4e-3)/sqrt(c), c=1
#define MINN 1e-15f

__device__ __forceinline__ float b2f(short s) {
    union { unsigned u; float f; } c; c.u = ((unsigned)(unsigned short)s) << 16; return c.f;
}
__device__ __forceinline__ short f2b(float f) {   // RNE bf16
    union { float f; unsigned u; } c; c.f = f;
    unsigned r = c.u + 0x7FFF + ((c.u >> 16) & 1);
    return (short)(r >> 16);
}
__device__ __forceinline__ float cv(short v) { return b2f(v); }
__device__ __forceinline__ float cv(float v) { return v; }
__device__ __forceinline__ short tb(short v) { return v; }
__device__ __forceinline__ short tb(float v) { return f2b(v); }
__device__ __forceinline__ short8 ld8(const short* p) { return *(const short8*)p; }
__device__ __forceinline__ short8 ld8(const float* p) {
    float4 a = *(const float4*)p, b = *(const float4*)(p + 4);
    short8 r;
    r[0] = f2b(a.x); r[1] = f2b(a.y); r[2] = f2b(a.z); r[3] = f2b(a.w);
    r[4] = f2b(b.x); r[5] = f2b(b.y); r[6] = f2b(b.z); r[7] = f2b(b.w);
    return r;
}
__device__ __forceinline__ void ldf8(const short* p, float* f) {
    short8 v = *(const short8*)p;
#pragma unroll
    for (int j = 0; j < 8; ++j) f[j] = b2f(v[j]);
}
__device__ __forceinline__ void ldf8(const float* p, float* f) {
    float4 a = *(const float4*)p, b = *(const float4*)(p + 4);
    f[0] = a.x; f[1] = a.y; f[2] = a.z; f[3] = a.w;
    f[4] = b.x; f[5] = b.y; f[6] = b.z; f[7] = b.w;
}
__device__ __forceinline__ void st(short* p, float v) { *p = f2b(v); }
__device__ __forceinline__ void st(float* p, float v) { *p = v; }

__device__ __forceinline__ float wave_sum(float v) {
#pragma unroll
    for (int m = 1; m < 64; m <<= 1) v += __shfl_xor(v, m);
    return v;
}
__device__ __forceinline__ float red16(float v) {
#pragma unroll
    for (int m = 1; m < 16; m <<= 1) v += __shfl_xor(v, m);
    return v;
}
__device__ __forceinline__ float artanh_(float x) {
    x = fminf(fmaxf(x, -1.f + 1e-7f), 1.f - 1e-7f);
    return 0.5f * (log1pf(x) - log1pf(-x));
}
__device__ __forceinline__ float sigmoidf_(float x) { return 1.f / (1.f + expf(-x)); }

// flag: 0 = storage is bf16, 1 = storage is f32
template <typename T> __device__ __forceinline__ bool skip(const int* flag) {
    return *flag != (int)(sizeof(T) == 4);
}

// ---------------- dtype detector ----------------
__global__ void k_detect(const void* hid, int* flag) {
    const short* p = (const short*)hid;
    int t = threadIdx.x;
    int bad = 0;
    for (int i = t; i < 4096; i += 256) {
        unsigned u = (unsigned)(unsigned short)p[i];
        unsigned ex = (u >> 7) & 0xFF;
        if (ex >= 128) bad = 1;   // |v| >= 2 or NaN/Inf -> cannot be in-ball bf16 data
    }
    __shared__ int s;
    if (t == 0) s = 0;
    __syncthreads();
    if (bad) atomicOr(&s, 1);
    __syncthreads();
    if (t == 0) *flag = s;
}

// ---------------- prep ----------------
template <typename T>
__global__ void k_prep(const T* __restrict__ b1, const T* __restrict__ b2,
                       const T* __restrict__ bl, const T* __restrict__ bih,
                       const T* __restrict__ bhh, const T* __restrict__ Q,
                       const T* __restrict__ ratt, const T* __restrict__ Wih,
                       const T* __restrict__ Whh,
                       float* hb1, float* y2a, float* hb2, float* y2b,
                       float* blf, float* bs256, float* ratf,
                       short* QT, short* Wc, const int* flag) {
    if (skip<T>(flag)) return;
    __shared__ float sb[256];
    int t = threadIdx.x;
    float v1 = (t < 128) ? cv(b1[t]) : 0.f;
    sb[t] = v1 * v1; __syncthreads();
    for (int d = 128; d > 0; d >>= 1) { if (t < d) sb[t] += sb[t + d]; __syncthreads(); }
    float n2a = sb[0]; __syncthreads();
    {
        float un = fmaxf(sqrtf(n2a), MINN);
        float e = tanhf(un), tt = e / un;
        float s = (e > MAXN) ? MAXN / e : 1.f;
        if (t < 128) hb1[t] = s * tt * v1;
        if (t == 0) { float hn = s * e; y2a[0] = hn * hn; }
    }
    float v2 = (t < 64) ? cv(b2[t]) : 0.f;
    sb[t] = v2 * v2; __syncthreads();
    for (int d = 128; d > 0; d >>= 1) { if (t < d) sb[t] += sb[t + d]; __syncthreads(); }
    float n2b = sb[0]; __syncthreads();
    {
        float un = fmaxf(sqrtf(n2b), MINN);
        float e = tanhf(un), tt = e / un;
        float s = (e > MAXN) ? MAXN / e : 1.f;
        if (t < 64) hb2[t] = s * tt * v2;
        if (t == 0) { float hn = s * e; y2b[0] = hn * hn; }
    }
    for (int i = t; i < 64; i += 256) {
        blf[i] = cv(bl[i]);
        ratf[i] = cv(ratt[i]);
    }
    {
        float v = (t < 192) ? (cv(bih[t]) + cv(bhh[t])) : cv(bhh[t - 64]);
        bs256[t] = v;
    }
    for (int i = t; i < 4096; i += 256) { int k = i >> 6, n = i & 63; QT[n * 64 + k] = tb(Q[k * 64 + n]); }
    for (int i = t; i < 256 * 128; i += 256) {
        int d = i >> 7, j = i & 127;
        short v;
        if (d < 192) v = (j < 64) ? tb(Wih[d * 64 + j]) : tb(Whh[d * 64 + (j - 64)]);
        else         v = (j < 64) ? (short)0 : tb(Whh[(d - 64) * 64 + (j - 64)]);
        Wc[i] = v;
    }
}

// ---------------- CSR ----------------
__global__ void k_zero(int* __restrict__ a, int* __restrict__ b, int N) {
    int i = blockIdx.x * blockDim.x + threadIdx.x;
    if (i < N) { a[i] = 0; b[i] = 0; }
}
__global__ void k_count(const int* __restrict__ src, int E, int* __restrict__ cnt) {
    int i = blockIdx.x * blockDim.x + threadIdx.x;
    if (i < E) atomicAdd(&cnt[src[i]], 1);
}

// ---- multi-block exclusive scan (replaces single-block k_scan) ----
// chunk = 2048 elems/block (256 thr x 8). Deterministic, bit-identical rowptr.
#define SC_CHUNK 2048
__global__ __launch_bounds__(256) void k_scan_bsum(const int* __restrict__ cnt, int N,
                                                   int* __restrict__ bsum) {
    __shared__ int sb[256];
    int t = threadIdx.x;
    int base = blockIdx.x * SC_CHUNK + t * 8;
    int s = 0;
#pragma unroll
    for (int j = 0; j < 8; ++j) { int i = base + j; if (i < N) s += cnt[i]; }
    sb[t] = s; __syncthreads();
    for (int d = 128; d > 0; d >>= 1) { if (t < d) sb[t] += sb[t + d]; __syncthreads(); }
    if (t == 0) bsum[blockIdx.x] = sb[0];
}
// single-block exclusive scan of nb (<=1024) block sums; bsum[nb] <- total
__global__ __launch_bounds__(1024) void k_scan_bpre(int* __restrict__ bsum, int nb) {
    __shared__ int sb[1024];
    int t = threadIdx.x;
    sb[t] = (t < nb) ? bsum[t] : 0;
    __syncthreads();
    for (int d = 1; d < 1024; d <<= 1) {
        int u = (t >= d) ? sb[t - d] : 0; __syncthreads();
        sb[t] += u; __syncthreads();
    }
    if (t < nb) bsum[t] = (t == 0) ? 0 : sb[t - 1];
    if (t == 0) bsum[nb] = sb[1023];
}
__global__ __launch_bounds__(256) void k_scan_write(const int* __restrict__ cnt,
                                                    int* __restrict__ rowptr, int N,
                                                    const int* __restrict__ bsum, int nb) {
    __shared__ int sb[256];
    int t = threadIdx.x;
    int b = blockIdx.x;
    int base = b * SC_CHUNK + t * 8;
    int v[8]; int s = 0;
#pragma unroll
    for (int j = 0; j < 8; ++j) { int i = base + j; v[j] = (i < N) ? cnt[i] : 0; s += v[j]; }
    sb[t] = s; __syncthreads();
    for (int d = 1; d < 256; d <<= 1) {
        int u = (t >= d) ? sb[t - d] : 0; __syncthreads();
        sb[t] += u; __syncthreads();
    }
    int run = bsum[b] + ((t == 0) ? 0 : sb[t - 1]);
#pragma unroll
    for (int j = 0; j < 8; ++j) {
        int i = base + j;
        if (i < N) rowptr[i] = run;
        run += v[j];
    }
    if (b == 0 && t == 0) rowptr[N] = bsum[nb];
}

__global__ void k_dis(const int* __restrict__ cnt, float* __restrict__ dis, int N) {
    int i = blockIdx.x * blockDim.x + threadIdx.x;
    if (i < N) dis[i] = 1.f / sqrtf((float)(cnt[i] + 1));
}
__global__ void k_fill(const int* __restrict__ src, const int* __restrict__ dst, int E,
                       const int* __restrict__ rowptr, int* __restrict__ fill, int* __restrict__ ecol) {
    int i = blockIdx.x * blockDim.x + threadIdx.x;
    if (i < E) {
        int s = src[i];
        int p = rowptr[s] + atomicAdd(&fill[s], 1);
        ecol[p] = dst[i];
    }
}

// --------- attention E: fused logmap0 -> (hlog@Q) -> tanh -> @r_att ------
// Also caches the per-row logmap0 scale lt = artanh(|p|)/|p| into Lt so the
// combine kernel (k_att_h) doesn't have to recompute norm+artanh per row.
template <typename T>
__global__ __launch_bounds__(256) void k_att_e(const T* __restrict__ hid,
                                               const short* __restrict__ QT,
                                               const float* __restrict__ ratf,
                                               float* __restrict__ Eo,
                                               float* __restrict__ Lt,
                                               int rows, const int* flag) {
    if (skip<T>(flag)) return;
    int wid = threadIdx.x >> 6, lane = threadIdx.x & 63;
    int row0 = blockIdx.x * 64 + wid * 16;
    if (row0 >= rows) return;
    int l15 = lane & 15, quad = lane >> 4;
    const T* Hrow = hid + (size_t)(row0 + l15) * 64 + quad * 8;
    float f0[8], f1[8];
    ldf8(Hrow, f0); ldf8(Hrow + 32, f1);
    float sq = 0.f;
#pragma unroll
    for (int j = 0; j < 8; ++j) sq += f0[j] * f0[j] + f1[j] * f1[j];
    sq += __shfl_xor(sq, 16); sq += __shfl_xor(sq, 32);
    float pn = fmaxf(sqrtf(sq), MINN);
    float lt = artanh_(pn) / pn;
    if (quad == 0) Lt[row0 + l15] = lt;   // cache for k_att_h
    short8 s0, s1;
#pragma unroll
    for (int j = 0; j < 8; ++j) { s0[j] = f2b(lt * f0[j]); s1[j] = f2b(lt * f1[j]); }
    f32x4 acc[4];
#pragma unroll
    for (int nt = 0; nt < 4; ++nt) acc[nt] = (f32x4){0.f, 0.f, 0.f, 0.f};
#pragma unroll
    for (int nt = 0; nt < 4; ++nt) {
        short8 b0 = *(const short8*)(QT + (size_t)(nt * 16 + l15) * 64 + quad * 8);
        short8 b1 = *(const short8*)(QT + (size_t)(nt * 16 + l15) * 64 + 32 + quad * 8);
        acc[nt] = __builtin_amdgcn_mfma_f32_16x16x32_bf16(s0, b0, acc[nt], 0, 0, 0);
        acc[nt] = __builtin_amdgcn_mfma_f32_16x16x32_bf16(s1, b1, acc[nt], 0, 0, 0);
    }
#pragma unroll
    for (int r = 0; r < 4; ++r) {
        float s = 0.f;
#pragma unroll
        for (int nt = 0; nt < 4; ++nt) s += tanhf(acc[nt][r]) * ratf[nt * 16 + l15];
        s = red16(s);
        if (l15 == 0) Eo[row0 + quad * 4 + r] = s;
    }
}

// --------- attention combine: softmax over window, h = mean(a*hlog) -----
// VALU-light version: reuses Lt (logmap0 scale) computed in k_att_e instead
// of re-deriving norm+artanh per (node, window). Memory-bound streaming.
template <typename T>
__global__ __launch_bounds__(256) void k_att_h(const float* __restrict__ Eb,
                                               const float* __restrict__ Lt,
                                               const T* __restrict__ hid,
                                               bf16* __restrict__ Hb, int N, int win, const int* flag) {
    if (skip<T>(flag)) return;
    int wid = threadIdx.x >> 6, lane = threadIdx.x & 63;
    int i = blockIdx.x * 4 + wid;
    if (i >= N) return;
    float hl[8], ev[8];
    float m = -1e30f;
    for (int w = 0; w < win; ++w) {
        float p = cv(hid[((size_t)w * N + i) * 64 + lane]);
        hl[w] = Lt[(size_t)w * N + i] * p;
        ev[w] = Eb[(size_t)w * N + i];
        m = fmaxf(m, ev[w]);
    }
    float s = 0.f;
    for (int w = 0; w < win; ++w) { ev[w] = expf(ev[w] - m); s += ev[w]; }
    float h = 0.f;
    for (int w = 0; w < win; ++w) h += ev[w] * hl[w];
    ((short*)Hb)[(size_t)i * 64 + lane] = f2b(h / (s * (float)win));
}

// --------- initial linear + expmap0/proj + concat hidden + proj128 ------
template <typename T>
__global__ __launch_bounds__(256) void k_lin0(const T* __restrict__ feat, const T* __restrict__ Wl,
                                              const float* __restrict__ blf, const T* __restrict__ hid,
                                              int win, float* __restrict__ xnorm,
                                              bf16* __restrict__ outA, int N, const int* flag) {
    if (skip<T>(flag)) return;
    int wid = threadIdx.x >> 6, lane = threadIdx.x & 63;
    int row0 = blockIdx.x * 64 + wid * 16;
    if (row0 >= N) return;
    int l15 = lane & 15, quad = lane >> 4;
    f32x4 acc[4];
#pragma unroll
    for (int nt = 0; nt < 4; ++nt) acc[nt] = (f32x4){0.f, 0.f, 0.f, 0.f};
    const T* Arow = feat + (size_t)(row0 + l15) * 128 + quad * 8;
    for (int k0 = 0; k0 < 128; k0 += 32) {
        short8 a = ld8(Arow + k0);
#pragma unroll
        for (int nt = 0; nt < 4; ++nt) {
            short8 b = ld8(Wl + (size_t)(nt * 16 + l15) * 128 + k0 + quad * 8);
            acc[nt] = __builtin_amdgcn_mfma_f32_16x16x32_bf16(a, b, acc[nt], 0, 0, 0);
        }
    }
    float bv[4];
#pragma unroll
    for (int nt = 0; nt < 4; ++nt) bv[nt] = blf[nt * 16 + l15];
#pragma unroll
    for (int r = 0; r < 4; ++r) {
        int row = row0 + quad * 4 + r;
        float g[4], u2 = 0.f;
#pragma unroll
        for (int nt = 0; nt < 4; ++nt) { g[nt] = acc[nt][r] + bv[nt]; u2 += g[nt] * g[nt]; }
        u2 = red16(u2);
        float un = fmaxf(sqrtf(u2), MINN);
        float e = tanhf(un), t = e / un;
        float s1 = (e > MAXN) ? MAXN / e : 1.f;
        float x0n = s1 * e;
        float hv[4], h2 = 0.f;
#pragma unroll
        for (int nt = 0; nt < 4; ++nt) {
            hv[nt] = cv(hid[((size_t)(win - 1) * N + row) * 64 + nt * 16 + l15]);
            h2 += hv[nt] * hv[nt];
        }
        h2 = red16(h2);
        float n128 = sqrtf(x0n * x0n + h2);
        float s2 = (n128 > MAXN) ? MAXN / n128 : 1.f;
#pragma unroll
        for (int nt = 0; nt < 4; ++nt) {
            ((short*)outA)[(size_t)row * 128 + nt * 16 + l15] = f2b(s2 * s1 * t * g[nt]);
            ((short*)outA)[(size_t)row * 128 + 64 + nt * 16 + l15] = f2b(s2 * hv[nt]);
        }
        if (l15 == 0) xnorm[row] = fmaxf(fminf(n128, MAXN), MINN);
    }
}

// ------- conv linear: GEMM fused with matvec->proj->madd(hb)->proj->logmap0 ----
template <int DOUT, typename T>
__global__ __launch_bounds__(256) void k_conv_lin(const bf16* __restrict__ in, const T* __restrict__ W,
                                                  const float* __restrict__ hb, const float* __restrict__ y2p,
                                                  const float* __restrict__ xnorm,
                                                  bf16* __restrict__ out, int N, const int* flag) {
    if (skip<T>(flag)) return;
    constexpr int NT = DOUT / 16;
    int wid = threadIdx.x >> 6, lane = threadIdx.x & 63;
    int row0 = blockIdx.x * 64 + wid * 16;
    if (row0 >= N) return;
    int l15 = lane & 15, quad = lane >> 4;
    f32x4 acc[NT];
#pragma unroll
    for (int nt = 0; nt < NT; ++nt) acc[nt] = (f32x4){0.f, 0.f, 0.f, 0.f};
    const short* Arow = (const short*)in + (size_t)(row0 + l15) * 128 + quad * 8;
    for (int k0 = 0; k0 < 128; k0 += 32) {
        short8 a = *(const short8*)(Arow + k0);
#pragma unroll
        for (int nt = 0; nt < NT; ++nt) {
            short8 b = ld8(W + (size_t)(nt * 16 + l15) * 128 + k0 + quad * 8);
            acc[nt] = __builtin_amdgcn_mfma_f32_16x16x32_bf16(a, b, acc[nt], 0, 0, 0);
        }
    }
    float y2 = y2p[0];
    float hbv[NT];
#pragma unroll
    for (int nt = 0; nt < NT; ++nt) hbv[nt] = hb[nt * 16 + l15];
#pragma unroll
    for (int r = 0; r < 4; ++r) {
        int row = row0 + quad * 4 + r;
        float mx[NT], m2 = 0.f;
#pragma unroll
        for (int nt = 0; nt < NT; ++nt) { mx[nt] = acc[nt][r]; m2 += mx[nt] * mx[nt]; }
        m2 = red16(m2);
        float mxn = fmaxf(sqrtf(m2), MINN);
        float xn = xnorm[row];
        float at = artanh_(xn);
        float f = (m2 == 0.f) ? 0.f : tanhf(mxn / xn * at) / mxn;
        float rn = f * mxn;
        float s1 = (rn > MAXN) ? MAXN / rn : 1.f;
        float a_ = s1 * f, mvn = s1 * rn;
        float x2 = mvn * mvn;
        float xy = 0.f;
#pragma unroll
        for (int nt = 0; nt < NT; ++nt) xy += (a_ * mx[nt]) * hbv[nt];
        xy = red16(xy);
        float co = 1.f + 2.f * xy + y2, cx = 1.f - x2;
        float den = fmaxf(1.f + 2.f * xy + x2 * y2, MINN);
        float o[NT], on2 = 0.f;
#pragma unroll
        for (int nt = 0; nt < NT; ++nt) { o[nt] = (co * a_ * mx[nt] + cx * hbv[nt]) / den; on2 += o[nt] * o[nt]; }
        on2 = red16(on2);
        float on = sqrtf(on2);
        float s3 = (on > MAXN) ? MAXN / on : 1.f;
        float hn = fmaxf(s3 * on, MINN);
        float lt = artanh_(hn) / hn;
#pragma unroll
        for (int nt = 0; nt < NT; ++nt)
            ((short*)out)[(size_t)row * 128 + nt * 16 + l15] = f2b(lt * s3 * o[nt]);
    }
}

// --------- aggregation + expmap0/proj + HypAct [+final logmap0] ----------
template <int DPL, bool FINAL>
__global__ __launch_bounds__(256) void k_agg(const bf16* __restrict__ xt, const int* __restrict__ rowptr,
                                             const int* __restrict__ ecol, const float* __restrict__ dis,
                                             bf16* __restrict__ out, float* __restrict__ xnorm,
                                             const bf16* __restrict__ Hb, int N) {
    int wid = threadIdx.x >> 6, lane = threadIdx.x & 63;
    int i = blockIdx.x * 4 + wid;
    if (i >= N) return;
    const short* xs = (const short*)xt;
    float di = dis[i];
    float w0 = di * di;
    float a0 = w0 * b2f(xs[(size_t)i * 128 + lane]);
    float a1 = 0.f;
    if (DPL == 2) a1 = w0 * b2f(xs[(size_t)i * 128 + 64 + lane]);
    int e0 = rowptr[i], e1 = rowptr[i + 1];
    for (int j = e0; j < e1; ++j) {
        int c = ecol[j];
        float w = di * dis[c];
        a0 += w * b2f(xs[(size_t)c * 128 + lane]);
        if (DPL == 2) a1 += w * b2f(xs[(size_t)c * 128 + 64 + lane]);
    }
    float an = fmaxf(sqrtf(wave_sum(a0 * a0 + a1 * a1)), MINN);
    float e1t = tanhf(an), t1 = e1t / an;
    float s1 = (e1t > MAXN) ? MAXN / e1t : 1.f;
    float hn = fmaxf(s1 * e1t, MINN);
    float lt = artanh_(hn) / hn;
    float sht = s1 * t1 * lt;
    float v0 = sht * a0; v0 = (v0 >= 0.f) ? v0 : 0.01f * v0;
    float v1 = sht * a1; v1 = (v1 >= 0.f) ? v1 : 0.01f * v1;
    float tn = fmaxf(sqrtf(wave_sum(v0 * v0 + v1 * v1)), MINN);
    float e2 = tanhf(tn), t2 = e2 / tn;
    float s2 = (e2 > MAXN) ? MAXN / e2 : 1.f;
    float sc = s2 * t2;
    float r0 = sc * v0, r1 = sc * v1;
    if (FINAL) {
        float xnf = fmaxf(fminf(s2 * e2, MAXN), MINN);
        float lt2 = artanh_(xnf) / xnf;
        r0 *= lt2; r1 *= lt2;
    }
    short* os = (short*)out;
    os[(size_t)i * 128 + lane] = f2b(r0);
    if (DPL == 2) {
        os[(size_t)i * 128 + 64 + lane] = f2b(r1);
        if (lane == 0 && xnorm) xnorm[i] = fmaxf(fminf(e2, MAXN), MINN);
    } else {
        os[(size_t)i * 128 + 64 + lane] = ((const short*)Hb)[(size_t)i * 64 + lane];
    }
}

// --------- GRU fused + expmap0/proj -> out (templated on OUT dtype) -----
template <typename OT>
__global__ __launch_bounds__(256) void k_gru_f(const bf16* __restrict__ cat, const short* __restrict__ Wc,
                                               const float* __restrict__ bs, const bf16* __restrict__ Hb,
                                               OT* __restrict__ out, int N, const int* flag) {
    if (skip<OT>(flag)) return;
    int wid = threadIdx.x >> 6, lane = threadIdx.x & 63;
    int row0 = blockIdx.x * 64 + wid * 16;
    if (row0 >= N) return;
    int l15 = lane & 15, quad = lane >> 4;
    f32x4 acc[16];
#pragma unroll
    for (int nt = 0; nt < 16; ++nt) acc[nt] = (f32x4){0.f, 0.f, 0.f, 0.f};
    const short* Arow = (const short*)cat + (size_t)(row0 + l15) * 128 + quad * 8;
    for (int k0 = 0; k0 < 128; k0 += 32) {
        short8 a = *(const short8*)(Arow + k0);
#pragma unroll
        for (int nt = 0; nt < 16; ++nt) {
            short8 b = *(const short8*)(Wc + (size_t)(nt * 16 + l15) * 128 + k0 + quad * 8);
            acc[nt] = __builtin_amdgcn_mfma_f32_16x16x32_bf16(a, b, acc[nt], 0, 0, 0);
        }
    }
#pragma unroll
    for (int r = 0; r < 4; ++r) {
        int row = row0 + quad * 4 + r;
        float zv[4], z2 = 0.f;
#pragma unroll
        for (int nt = 0; nt < 4; ++nt) {
            int c = nt * 16 + l15;
            float gr = acc[nt][r] + bs[c];
            float gz = acc[nt + 4][r] + bs[c + 64];
            float gn = acc[nt + 8][r] + bs[c + 128];
            float hn = acc[nt + 12][r] + bs[c + 192];
            float hv = b2f(((const short*)Hb)[(size_t)row * 64 + c]);
            float rr = sigmoidf_(gr), zz = sigmoidf_(gz);
            float nn = tanhf(gn + (rr - 1.f) * hn);
            zv[nt] = (1.f - zz) * nn + zz * hv;
            z2 += zv[nt] * zv[nt];
        }
        z2 = red16(z2);
        float un = fmaxf(sqrtf(z2), MINN);
        float e = tanhf(un), t = e / un;
        float s = (e > MAXN) ? MAXN / e : 1.f;
#pragma unroll
        for (int nt = 0; nt < 4; ++nt)
            st(&out[(size_t)row * 64 + nt * 16 + l15], s * t * zv[nt]);
    }
}

extern "C" void kernel_launch(void* const* d_in, const int* in_sizes, int n_in,
                              void* d_out, int out_size, void* d_ws, size_t ws_size,
                              hipStream_t stream) {
    const int E = in_sizes[0] / 2;
    const int N = in_sizes[1] / 128;
    int win = in_sizes[14] / (N * 64); if (win > 8) win = 8;

    char* wp = (char*)d_ws;
    auto alloc = [&](size_t bytes) -> void* {
        void* p = (void*)wp;
        wp += (bytes + 255) & ~(size_t)255;
        return p;
    };
    bf16* bufA = (bf16*)alloc((size_t)N * 128 * 2);
    bf16* bufB = (bf16*)alloc((size_t)N * 128 * 2);
    bf16* Hbf  = (bf16*)alloc((size_t)N * 64 * 2);
    float* Ebuf = (float*)alloc((size_t)win * N * 4);
    float* Ltb  = (float*)alloc((size_t)win * N * 4);
    float* xnorm = (float*)alloc((size_t)N * 4);
    int* cnt = (int*)alloc((size_t)N * 4);
    int* fillc = (int*)alloc((size_t)N * 4);
    int* rowptr = (int*)alloc((size_t)(N + 1) * 4);
    float* dis = (float*)alloc((size_t)N * 4);
    int* ecol = (int*)alloc((size_t)E * 4);
    int* bsum = (int*)alloc((size_t)1025 * 4);
    float* hb1 = (float*)alloc(128 * 4);
    float* y2a = (float*)alloc(256);
    float* hb2 = (float*)alloc(64 * 4);
    float* y2b = (float*)alloc(256);
    float* blf = (float*)alloc(64 * 4);
    float* bs256 = (float*)alloc(256 * 4);
    float* ratf = (float*)alloc(64 * 4);
    short* QT = (short*)alloc(4096 * 2);
    short* Wc = (short*)alloc((size_t)256 * 128 * 2);
    int* flag = (int*)alloc(256);
    (void)ws_size; (void)out_size; (void)n_in;

    const int* ei = (const int*)d_in[0];

    k_detect<<<1, 256, 0, stream>>>(d_in[14], flag);

    // prep (both dtype variants; non-matching exits immediately)
#define P(T) (const T*)d_in
    k_prep<short><<<1, 256, 0, stream>>>(P(short)[5], P(short)[7], P(short)[3], P(short)[12], P(short)[13],
                                         P(short)[8], P(short)[9], P(short)[10], P(short)[11],
                                         hb1, y2a, hb2, y2b, blf, bs256, ratf, QT, Wc, flag);
    k_prep<float><<<1, 256, 0, stream>>>(P(float)[5], P(float)[7], P(float)[3], P(float)[12], P(float)[13],
                                         P(float)[8], P(float)[9], P(float)[10], P(float)[11],
                                         hb1, y2a, hb2, y2b, blf, bs256, ratf, QT, Wc, flag);
    // CSR build (dtype-free)
    k_zero<<<(N + 255) / 256, 256, 0, stream>>>(cnt, fillc, N);
    k_count<<<(E + 255) / 256, 256, 0, stream>>>(ei, E, cnt);
    {
        int nb = (N + SC_CHUNK - 1) / SC_CHUNK;   // <=1024 for N<=2M
        k_scan_bsum<<<nb, 256, 0, stream>>>(cnt, N, bsum);
        k_scan_bpre<<<1, 1024, 0, stream>>>(bsum, nb);
        k_scan_write<<<nb, 256, 0, stream>>>(cnt, rowptr, N, bsum, nb);
    }
    k_dis<<<(N + 255) / 256, 256, 0, stream>>>(cnt, dis, N);
    k_fill<<<(E + 255) / 256, 256, 0, stream>>>(ei, ei + E, E, rowptr, fillc, ecol);
    // HTA window attention
    int rowsHL = win * N;
    k_att_e<short><<<(rowsHL + 63) / 64, 256, 0, stream>>>(P(short)[14], QT, ratf, Ebuf, Ltb, rowsHL, flag);
    k_att_e<float><<<(rowsHL + 63) / 64, 256, 0, stream>>>(P(float)[14], QT, ratf, Ebuf, Ltb, rowsHL, flag);
    k_att_h<short><<<(N + 3) / 4, 256, 0, stream>>>(Ebuf, Ltb, P(short)[14], Hbf, N, win, flag);
    k_att_h<float><<<(N + 3) / 4, 256, 0, stream>>>(Ebuf, Ltb, P(float)[14], Hbf, N, win, flag);
    // initial linear + toHyperX + concat
    k_lin0<short><<<(N + 63) / 64, 256, 0, stream>>>(P(short)[1], P(short)[2], blf, P(short)[14], win, xnorm, bufA, N, flag);
    k_lin0<float><<<(N + 63) / 64, 256, 0, stream>>>(P(float)[1], P(float)[2], blf, P(float)[14], win, xnorm, bufA, N, flag);
    // conv1
    k_conv_lin<128, short><<<(N + 63) / 64, 256, 0, stream>>>(bufA, P(short)[4], hb1, y2a, xnorm, bufA, N, flag);
    k_conv_lin<128, float><<<(N + 63) / 64, 256, 0, stream>>>(bufA, P(float)[4], hb1, y2a, xnorm, bufA, N, flag);
    k_agg<2, false><<<(N + 3) / 4, 256, 0, stream>>>(bufA, rowptr, ecol, dis, bufB, xnorm, nullptr, N);
    // conv2
    k_conv_lin<64, short><<<(N + 63) / 64, 256, 0, stream>>>(bufB, P(short)[6], hb2, y2b, xnorm, bufB, N, flag);
    k_conv_lin<64, float><<<(N + 63) / 64, 256, 0, stream>>>(bufB, P(float)[6], hb2, y2b, xnorm, bufB, N, flag);
    k_agg<1, true><<<(N + 3) / 4, 256, 0, stream>>>(bufB, rowptr, ecol, dis, bufA, nullptr, Hbf, N);
    // GRU fused + toHyperX -> out (output dtype = detected input dtype)
    k_gru_f<short><<<(N + 63) / 64, 256, 0, stream>>>(bufA, Wc, bs256, Hbf, (short*)d_out, N, flag);
    k_gru_f<float><<<(N + 63) / 64, 256, 0, stream>>>(bufA, Wc, bs256, Hbf, (float*)d_out, N, flag);
#undef P
}

// Round 3
// 913.247 us; speedup vs baseline: 1.3919x; 1.0577x over previous
//
#include <hip/hip_runtime.h>
#include <hip/hip_bf16.h>

typedef __hip_bfloat16 bf16;
typedef __attribute__((ext_vector_type(8))) short short8;
typedef __attribute__((ext_vector_type(4))) float f32x4;

#define MAXN 0.996f      // (1 - 4e-3)/sqrt(c), c=1
#define MINN 1e-15f

__device__ __forceinline__ float b2f(short s) {
    union { unsigned u; float f; } c; c.u = ((unsigned)(unsigned short)s) << 16; return c.f;
}
__device__ __forceinline__ short f2b(float f) {   // RNE bf16
    union { float f; unsigned u; } c; c.f = f;
    unsigned r = c.u + 0x7FFF + ((c.u >> 16) & 1);
    return (short)(r >> 16);
}
__device__ __forceinline__ float lo16f(unsigned u) {
    union { unsigned u; float f; } c; c.u = u << 16; return c.f;
}
__device__ __forceinline__ float hi16f(unsigned u) {
    union { unsigned u; float f; } c; c.u = u & 0xFFFF0000u; return c.f;
}
__device__ __forceinline__ unsigned pk2(float x, float y) {
    return (unsigned)(unsigned short)f2b(x) | ((unsigned)(unsigned short)f2b(y) << 16);
}
__device__ __forceinline__ float cv(short v) { return b2f(v); }
__device__ __forceinline__ float cv(float v) { return v; }
__device__ __forceinline__ short tb(short v) { return v; }
__device__ __forceinline__ short tb(float v) { return f2b(v); }
__device__ __forceinline__ short8 ld8(const short* p) { return *(const short8*)p; }
__device__ __forceinline__ short8 ld8(const float* p) {
    float4 a = *(const float4*)p, b = *(const float4*)(p + 4);
    short8 r;
    r[0] = f2b(a.x); r[1] = f2b(a.y); r[2] = f2b(a.z); r[3] = f2b(a.w);
    r[4] = f2b(b.x); r[5] = f2b(b.y); r[6] = f2b(b.z); r[7] = f2b(b.w);
    return r;
}
__device__ __forceinline__ void ldf8(const short* p, float* f) {
    short8 v = *(const short8*)p;
#pragma unroll
    for (int j = 0; j < 8; ++j) f[j] = b2f(v[j]);
}
__device__ __forceinline__ void ldf8(const float* p, float* f) {
    float4 a = *(const float4*)p, b = *(const float4*)(p + 4);
    f[0] = a.x; f[1] = a.y; f[2] = a.z; f[3] = a.w;
    f[4] = b.x; f[5] = b.y; f[6] = b.z; f[7] = b.w;
}
__device__ __forceinline__ void st(short* p, float v) { *p = f2b(v); }
__device__ __forceinline__ void st(float* p, float v) { *p = v; }

__device__ __forceinline__ float wave_sum(float v) {
#pragma unroll
    for (int m = 1; m < 64; m <<= 1) v += __shfl_xor(v, m);
    return v;
}
__device__ __forceinline__ float red32(float v) {
#pragma unroll
    for (int m = 1; m < 32; m <<= 1) v += __shfl_xor(v, m);
    return v;
}
__device__ __forceinline__ float red16(float v) {
#pragma unroll
    for (int m = 1; m < 16; m <<= 1) v += __shfl_xor(v, m);
    return v;
}
__device__ __forceinline__ float artanh_(float x) {
    x = fminf(fmaxf(x, -1.f + 1e-7f), 1.f - 1e-7f);
    return 0.5f * (log1pf(x) - log1pf(-x));
}
__device__ __forceinline__ float sigmoidf_(float x) { return 1.f / (1.f + expf(-x)); }

// flag: 0 = storage is bf16, 1 = storage is f32
template <typename T> __device__ __forceinline__ bool skip(const int* flag) {
    return *flag != (int)(sizeof(T) == 4);
}

// ---------------- dtype detector ----------------
__global__ void k_detect(const void* hid, int* flag) {
    const short* p = (const short*)hid;
    int t = threadIdx.x;
    int bad = 0;
    for (int i = t; i < 4096; i += 256) {
        unsigned u = (unsigned)(unsigned short)p[i];
        unsigned ex = (u >> 7) & 0xFF;
        if (ex >= 128) bad = 1;   // |v| >= 2 or NaN/Inf -> cannot be in-ball bf16 data
    }
    __shared__ int s;
    if (t == 0) s = 0;
    __syncthreads();
    if (bad) atomicOr(&s, 1);
    __syncthreads();
    if (t == 0) *flag = s;
}

// ---------------- prep ----------------
template <typename T>
__global__ void k_prep(const T* __restrict__ b1, const T* __restrict__ b2,
                       const T* __restrict__ bl, const T* __restrict__ bih,
                       const T* __restrict__ bhh, const T* __restrict__ Q,
                       const T* __restrict__ ratt, const T* __restrict__ Wih,
                       const T* __restrict__ Whh,
                       float* hb1, float* y2a, float* hb2, float* y2b,
                       float* blf, float* bs256, float* ratf,
                       short* QT, short* Wc, const int* flag) {
    if (skip<T>(flag)) return;
    __shared__ float sb[256];
    int t = threadIdx.x;
    float v1 = (t < 128) ? cv(b1[t]) : 0.f;
    sb[t] = v1 * v1; __syncthreads();
    for (int d = 128; d > 0; d >>= 1) { if (t < d) sb[t] += sb[t + d]; __syncthreads(); }
    float n2a = sb[0]; __syncthreads();
    {
        float un = fmaxf(sqrtf(n2a), MINN);
        float e = tanhf(un), tt = e / un;
        float s = (e > MAXN) ? MAXN / e : 1.f;
        if (t < 128) hb1[t] = s * tt * v1;
        if (t == 0) { float hn = s * e; y2a[0] = hn * hn; }
    }
    float v2 = (t < 64) ? cv(b2[t]) : 0.f;
    sb[t] = v2 * v2; __syncthreads();
    for (int d = 128; d > 0; d >>= 1) { if (t < d) sb[t] += sb[t + d]; __syncthreads(); }
    float n2b = sb[0]; __syncthreads();
    {
        float un = fmaxf(sqrtf(n2b), MINN);
        float e = tanhf(un), tt = e / un;
        float s = (e > MAXN) ? MAXN / e : 1.f;
        if (t < 64) hb2[t] = s * tt * v2;
        if (t == 0) { float hn = s * e; y2b[0] = hn * hn; }
    }
    for (int i = t; i < 64; i += 256) {
        blf[i] = cv(bl[i]);
        ratf[i] = cv(ratt[i]);
    }
    {
        float v = (t < 192) ? (cv(bih[t]) + cv(bhh[t])) : cv(bhh[t - 64]);
        bs256[t] = v;
    }
    for (int i = t; i < 4096; i += 256) { int k = i >> 6, n = i & 63; QT[n * 64 + k] = tb(Q[k * 64 + n]); }
    for (int i = t; i < 256 * 128; i += 256) {
        int d = i >> 7, j = i & 127;
        short v;
        if (d < 192) v = (j < 64) ? tb(Wih[d * 64 + j]) : tb(Whh[d * 64 + (j - 64)]);
        else         v = (j < 64) ? (short)0 : tb(Whh[(d - 64) * 64 + (j - 64)]);
        Wc[i] = v;
    }
}

// ---------------- CSR ----------------
__global__ void k_zero(int* __restrict__ a, int* __restrict__ b, int N) {
    int i = blockIdx.x * blockDim.x + threadIdx.x;
    if (i < N) { a[i] = 0; b[i] = 0; }
}
__global__ void k_count(const int* __restrict__ src, int E, int* __restrict__ cnt) {
    int i = blockIdx.x * blockDim.x + threadIdx.x;
    if (i < E) atomicAdd(&cnt[src[i]], 1);
}

// ---- multi-block exclusive scan ----
#define SC_CHUNK 2048
__global__ __launch_bounds__(256) void k_scan_bsum(const int* __restrict__ cnt, int N,
                                                   int* __restrict__ bsum) {
    __shared__ int sb[256];
    int t = threadIdx.x;
    int base = blockIdx.x * SC_CHUNK + t * 8;
    int s = 0;
#pragma unroll
    for (int j = 0; j < 8; ++j) { int i = base + j; if (i < N) s += cnt[i]; }
    sb[t] = s; __syncthreads();
    for (int d = 128; d > 0; d >>= 1) { if (t < d) sb[t] += sb[t + d]; __syncthreads(); }
    if (t == 0) bsum[blockIdx.x] = sb[0];
}
__global__ __launch_bounds__(1024) void k_scan_bpre(int* __restrict__ bsum, int nb) {
    __shared__ int sb[1024];
    int t = threadIdx.x;
    sb[t] = (t < nb) ? bsum[t] : 0;
    __syncthreads();
    for (int d = 1; d < 1024; d <<= 1) {
        int u = (t >= d) ? sb[t - d] : 0; __syncthreads();
        sb[t] += u; __syncthreads();
    }
    if (t < nb) bsum[t] = (t == 0) ? 0 : sb[t - 1];
    if (t == 0) bsum[nb] = sb[1023];
}
__global__ __launch_bounds__(256) void k_scan_write(const int* __restrict__ cnt,
                                                    int* __restrict__ rowptr, int N,
                                                    const int* __restrict__ bsum, int nb) {
    __shared__ int sb[256];
    int t = threadIdx.x;
    int b = blockIdx.x;
    int base = b * SC_CHUNK + t * 8;
    int v[8]; int s = 0;
#pragma unroll
    for (int j = 0; j < 8; ++j) { int i = base + j; v[j] = (i < N) ? cnt[i] : 0; s += v[j]; }
    sb[t] = s; __syncthreads();
    for (int d = 1; d < 256; d <<= 1) {
        int u = (t >= d) ? sb[t - d] : 0; __syncthreads();
        sb[t] += u; __syncthreads();
    }
    int run = bsum[b] + ((t == 0) ? 0 : sb[t - 1]);
#pragma unroll
    for (int j = 0; j < 8; ++j) {
        int i = base + j;
        if (i < N) rowptr[i] = run;
        run += v[j];
    }
    if (b == 0 && t == 0) rowptr[N] = bsum[nb];
}

__global__ void k_dis(const int* __restrict__ cnt, float* __restrict__ dis, int N) {
    int i = blockIdx.x * blockDim.x + threadIdx.x;
    if (i < N) dis[i] = 1.f / sqrtf((float)(cnt[i] + 1));
}
// fill also precomputes per-edge GCN weight ew = dis[src]*dis[dst]
__global__ void k_fill(const int* __restrict__ src, const int* __restrict__ dst, int E,
                       const int* __restrict__ rowptr, int* __restrict__ fill,
                       int* __restrict__ ecol, const float* __restrict__ dis,
                       float* __restrict__ ew) {
    int i = blockIdx.x * blockDim.x + threadIdx.x;
    if (i < E) {
        int s = src[i], d = dst[i];
        int p = rowptr[s] + atomicAdd(&fill[s], 1);
        ecol[p] = d;
        ew[p] = dis[s] * dis[d];
    }
}

// --------- attention E: fused logmap0 -> (hlog@Q) -> tanh -> @r_att ------
template <typename T>
__global__ __launch_bounds__(256) void k_att_e(const T* __restrict__ hid,
                                               const short* __restrict__ QT,
                                               const float* __restrict__ ratf,
                                               float* __restrict__ Eo,
                                               float* __restrict__ Lt,
                                               int rows, const int* flag) {
    if (skip<T>(flag)) return;
    int wid = threadIdx.x >> 6, lane = threadIdx.x & 63;
    int row0 = blockIdx.x * 64 + wid * 16;
    if (row0 >= rows) return;
    int l15 = lane & 15, quad = lane >> 4;
    const T* Hrow = hid + (size_t)(row0 + l15) * 64 + quad * 8;
    float f0[8], f1[8];
    ldf8(Hrow, f0); ldf8(Hrow + 32, f1);
    float sq = 0.f;
#pragma unroll
    for (int j = 0; j < 8; ++j) sq += f0[j] * f0[j] + f1[j] * f1[j];
    sq += __shfl_xor(sq, 16); sq += __shfl_xor(sq, 32);
    float pn = fmaxf(sqrtf(sq), MINN);
    float lt = artanh_(pn) / pn;
    if (quad == 0) Lt[row0 + l15] = lt;   // cache for k_att_h
    short8 s0, s1;
#pragma unroll
    for (int j = 0; j < 8; ++j) { s0[j] = f2b(lt * f0[j]); s1[j] = f2b(lt * f1[j]); }
    f32x4 acc[4];
#pragma unroll
    for (int nt = 0; nt < 4; ++nt) acc[nt] = (f32x4){0.f, 0.f, 0.f, 0.f};
#pragma unroll
    for (int nt = 0; nt < 4; ++nt) {
        short8 b0 = *(const short8*)(QT + (size_t)(nt * 16 + l15) * 64 + quad * 8);
        short8 b1 = *(const short8*)(QT + (size_t)(nt * 16 + l15) * 64 + 32 + quad * 8);
        acc[nt] = __builtin_amdgcn_mfma_f32_16x16x32_bf16(s0, b0, acc[nt], 0, 0, 0);
        acc[nt] = __builtin_amdgcn_mfma_f32_16x16x32_bf16(s1, b1, acc[nt], 0, 0, 0);
    }
#pragma unroll
    for (int r = 0; r < 4; ++r) {
        float s = 0.f;
#pragma unroll
        for (int nt = 0; nt < 4; ++nt) s += tanhf(acc[nt][r]) * ratf[nt * 16 + l15];
        s = red16(s);
        if (l15 == 0) Eo[row0 + quad * 4 + r] = s;
    }
}

// --------- attention combine: softmax over window, h = mean(a*hlog) -----
template <typename T>
__global__ __launch_bounds__(256) void k_att_h(const float* __restrict__ Eb,
                                               const float* __restrict__ Lt,
                                               const T* __restrict__ hid,
                                               bf16* __restrict__ Hb, int N, int win, const int* flag) {
    if (skip<T>(flag)) return;
    int wid = threadIdx.x >> 6, lane = threadIdx.x & 63;
    int i = blockIdx.x * 4 + wid;
    if (i >= N) return;
    float hl[8], ev[8];
    float m = -1e30f;
    for (int w = 0; w < win; ++w) {
        float p = cv(hid[((size_t)w * N + i) * 64 + lane]);
        hl[w] = Lt[(size_t)w * N + i] * p;
        ev[w] = Eb[(size_t)w * N + i];
        m = fmaxf(m, ev[w]);
    }
    float s = 0.f;
    for (int w = 0; w < win; ++w) { ev[w] = expf(ev[w] - m); s += ev[w]; }
    float h = 0.f;
    for (int w = 0; w < win; ++w) h += ev[w] * hl[w];
    ((short*)Hb)[(size_t)i * 64 + lane] = f2b(h / (s * (float)win));
}

// --------- initial linear + expmap0/proj + concat hidden + proj128 ------
template <typename T>
__global__ __launch_bounds__(256) void k_lin0(const T* __restrict__ feat, const T* __restrict__ Wl,
                                              const float* __restrict__ blf, const T* __restrict__ hid,
                                              int win, float* __restrict__ xnorm,
                                              bf16* __restrict__ outA, int N, const int* flag) {
    if (skip<T>(flag)) return;
    int wid = threadIdx.x >> 6, lane = threadIdx.x & 63;
    int row0 = blockIdx.x * 64 + wid * 16;
    if (row0 >= N) return;
    int l15 = lane & 15, quad = lane >> 4;
    f32x4 acc[4];
#pragma unroll
    for (int nt = 0; nt < 4; ++nt) acc[nt] = (f32x4){0.f, 0.f, 0.f, 0.f};
    const T* Arow = feat + (size_t)(row0 + l15) * 128 + quad * 8;
    for (int k0 = 0; k0 < 128; k0 += 32) {
        short8 a = ld8(Arow + k0);
#pragma unroll
        for (int nt = 0; nt < 4; ++nt) {
            short8 b = ld8(Wl + (size_t)(nt * 16 + l15) * 128 + k0 + quad * 8);
            acc[nt] = __builtin_amdgcn_mfma_f32_16x16x32_bf16(a, b, acc[nt], 0, 0, 0);
        }
    }
    float bv[4];
#pragma unroll
    for (int nt = 0; nt < 4; ++nt) bv[nt] = blf[nt * 16 + l15];
#pragma unroll
    for (int r = 0; r < 4; ++r) {
        int row = row0 + quad * 4 + r;
        float g[4], u2 = 0.f;
#pragma unroll
        for (int nt = 0; nt < 4; ++nt) { g[nt] = acc[nt][r] + bv[nt]; u2 += g[nt] * g[nt]; }
        u2 = red16(u2);
        float un = fmaxf(sqrtf(u2), MINN);
        float e = tanhf(un), t = e / un;
        float s1 = (e > MAXN) ? MAXN / e : 1.f;
        float x0n = s1 * e;
        float hv[4], h2 = 0.f;
#pragma unroll
        for (int nt = 0; nt < 4; ++nt) {
            hv[nt] = cv(hid[((size_t)(win - 1) * N + row) * 64 + nt * 16 + l15]);
            h2 += hv[nt] * hv[nt];
        }
        h2 = red16(h2);
        float n128 = sqrtf(x0n * x0n + h2);
        float s2 = (n128 > MAXN) ? MAXN / n128 : 1.f;
#pragma unroll
        for (int nt = 0; nt < 4; ++nt) {
            ((short*)outA)[(size_t)row * 128 + nt * 16 + l15] = f2b(s2 * s1 * t * g[nt]);
            ((short*)outA)[(size_t)row * 128 + 64 + nt * 16 + l15] = f2b(s2 * hv[nt]);
        }
        if (l15 == 0) xnorm[row] = fmaxf(fminf(n128, MAXN), MINN);
    }
}

// ------- conv linear: GEMM fused with matvec->proj->madd(hb)->proj->logmap0 ----
template <int DOUT, typename T>
__global__ __launch_bounds__(256) void k_conv_lin(const bf16* __restrict__ in, const T* __restrict__ W,
                                                  const float* __restrict__ hb, const float* __restrict__ y2p,
                                                  const float* __restrict__ xnorm,
                                                  bf16* __restrict__ out, int N, const int* flag) {
    if (skip<T>(flag)) return;
    constexpr int NT = DOUT / 16;
    int wid = threadIdx.x >> 6, lane = threadIdx.x & 63;
    int row0 = blockIdx.x * 64 + wid * 16;
    if (row0 >= N) return;
    int l15 = lane & 15, quad = lane >> 4;
    f32x4 acc[NT];
#pragma unroll
    for (int nt = 0; nt < NT; ++nt) acc[nt] = (f32x4){0.f, 0.f, 0.f, 0.f};
    const short* Arow = (const short*)in + (size_t)(row0 + l15) * 128 + quad * 8;
    for (int k0 = 0; k0 < 128; k0 += 32) {
        short8 a = *(const short8*)(Arow + k0);
#pragma unroll
        for (int nt = 0; nt < NT; ++nt) {
            short8 b = ld8(W + (size_t)(nt * 16 + l15) * 128 + k0 + quad * 8);
            acc[nt] = __builtin_amdgcn_mfma_f32_16x16x32_bf16(a, b, acc[nt], 0, 0, 0);
        }
    }
    float y2 = y2p[0];
    float hbv[NT];
#pragma unroll
    for (int nt = 0; nt < NT; ++nt) hbv[nt] = hb[nt * 16 + l15];
#pragma unroll
    for (int r = 0; r < 4; ++r) {
        int row = row0 + quad * 4 + r;
        float mx[NT], m2 = 0.f;
#pragma unroll
        for (int nt = 0; nt < NT; ++nt) { mx[nt] = acc[nt][r]; m2 += mx[nt] * mx[nt]; }
        m2 = red16(m2);
        float mxn = fmaxf(sqrtf(m2), MINN);
        float xn = xnorm[row];
        float at = artanh_(xn);
        float f = (m2 == 0.f) ? 0.f : tanhf(mxn / xn * at) / mxn;
        float rn = f * mxn;
        float s1 = (rn > MAXN) ? MAXN / rn : 1.f;
        float a_ = s1 * f, mvn = s1 * rn;
        float x2 = mvn * mvn;
        float xy = 0.f;
#pragma unroll
    for (int nt = 0; nt < NT; ++nt) xy += (a_ * mx[nt]) * hbv[nt];
        xy = red16(xy);
        float co = 1.f + 2.f * xy + y2, cx = 1.f - x2;
        float den = fmaxf(1.f + 2.f * xy + x2 * y2, MINN);
        float o[NT], on2 = 0.f;
#pragma unroll
        for (int nt = 0; nt < NT; ++nt) { o[nt] = (co * a_ * mx[nt] + cx * hbv[nt]) / den; on2 += o[nt] * o[nt]; }
        on2 = red16(on2);
        float on = sqrtf(on2);
        float s3 = (on > MAXN) ? MAXN / on : 1.f;
        float hn = fmaxf(s3 * on, MINN);
        float lt = artanh_(hn) / hn;
#pragma unroll
        for (int nt = 0; nt < NT; ++nt)
            ((short*)out)[(size_t)row * 128 + nt * 16 + l15] = f2b(lt * s3 * o[nt]);
    }
}

// --------- agg (conv1, D=128): one node/wave, 2 features/lane via dword ----
__global__ __launch_bounds__(256) void k_agg2(const bf16* __restrict__ xt, const int* __restrict__ rowptr,
                                              const int* __restrict__ ecol, const float* __restrict__ ew,
                                              const float* __restrict__ dis,
                                              bf16* __restrict__ out, float* __restrict__ xnorm, int N) {
    int wid = threadIdx.x >> 6, lane = threadIdx.x & 63;
    int i = blockIdx.x * 4 + wid;
    if (i >= N) return;
    const unsigned* xd = (const unsigned*)xt;          // 64 dwords per 128-feat row
    float di = dis[i];
    float w0 = di * di;
    unsigned d0 = xd[(size_t)i * 64 + lane];
    float a0 = w0 * lo16f(d0), a1 = w0 * hi16f(d0);    // features 2*lane, 2*lane+1
    int e0 = rowptr[i], e1 = rowptr[i + 1];
    for (int j = e0; j < e1; ++j) {
        int c = ecol[j];
        float w = ew[j];
        unsigned d = xd[(size_t)c * 64 + lane];
        a0 += w * lo16f(d);
        a1 += w * hi16f(d);
    }
    float an = fmaxf(sqrtf(wave_sum(a0 * a0 + a1 * a1)), MINN);
    float e1t = tanhf(an), t1 = e1t / an;
    float s1 = (e1t > MAXN) ? MAXN / e1t : 1.f;
    float hn = fmaxf(s1 * e1t, MINN);
    float lt = artanh_(hn) / hn;
    float sht = s1 * t1 * lt;
    float v0 = sht * a0; v0 = (v0 >= 0.f) ? v0 : 0.01f * v0;
    float v1 = sht * a1; v1 = (v1 >= 0.f) ? v1 : 0.01f * v1;
    float tn = fmaxf(sqrtf(wave_sum(v0 * v0 + v1 * v1)), MINN);
    float e2 = tanhf(tn), t2 = e2 / tn;
    float s2 = (e2 > MAXN) ? MAXN / e2 : 1.f;
    float sc = s2 * t2;
    ((unsigned*)out)[(size_t)i * 64 + lane] = pk2(sc * v0, sc * v1);
    if (lane == 0) xnorm[i] = fmaxf(fminf(e2, MAXN), MINN);
}

// --------- agg (conv2, D=64) + FINAL logmap0: two nodes/wave -------------
__global__ __launch_bounds__(256) void k_agg1f(const bf16* __restrict__ xt, const int* __restrict__ rowptr,
                                               const int* __restrict__ ecol, const float* __restrict__ ew,
                                               const float* __restrict__ dis,
                                               bf16* __restrict__ out, const bf16* __restrict__ Hb, int N) {
    int wid = threadIdx.x >> 6, lane = threadIdx.x & 63;
    int half = lane >> 5, l31 = lane & 31;
    int i = blockIdx.x * 8 + wid * 2 + half;
    bool act = (i < N);
    int ii = act ? i : (N - 1);
    const unsigned* xd = (const unsigned*)xt;          // first 64 feats = dwords 0..31
    float di = dis[ii];
    float w0 = di * di;
    unsigned d0 = xd[(size_t)ii * 64 + l31];
    float a0 = w0 * lo16f(d0), a1 = w0 * hi16f(d0);    // features 2*l31, 2*l31+1
    int e0 = rowptr[ii], e1 = act ? rowptr[ii + 1] : e0;
    for (int j = e0; j < e1; ++j) {
        int c = ecol[j];
        float w = ew[j];
        unsigned d = xd[(size_t)c * 64 + l31];
        a0 += w * lo16f(d);
        a1 += w * hi16f(d);
    }
    float an = fmaxf(sqrtf(red32(a0 * a0 + a1 * a1)), MINN);
    float e1t = tanhf(an), t1 = e1t / an;
    float s1 = (e1t > MAXN) ? MAXN / e1t : 1.f;
    float hn = fmaxf(s1 * e1t, MINN);
    float lt = artanh_(hn) / hn;
    float sht = s1 * t1 * lt;
    float v0 = sht * a0; v0 = (v0 >= 0.f) ? v0 : 0.01f * v0;
    float v1 = sht * a1; v1 = (v1 >= 0.f) ? v1 : 0.01f * v1;
    float tn = fmaxf(sqrtf(red32(v0 * v0 + v1 * v1)), MINN);
    float e2 = tanhf(tn), t2 = e2 / tn;
    float s2 = (e2 > MAXN) ? MAXN / e2 : 1.f;
    float sc = s2 * t2;
    float r0 = sc * v0, r1 = sc * v1;
    float xnf = fmaxf(fminf(s2 * e2, MAXN), MINN);
    float lt2 = artanh_(xnf) / xnf;
    r0 *= lt2; r1 *= lt2;
    if (act) {
        unsigned* od = (unsigned*)out;
        od[(size_t)i * 64 + l31] = pk2(r0, r1);
        od[(size_t)i * 64 + 32 + l31] = ((const unsigned*)Hb)[(size_t)i * 32 + l31];
    }
}

// --------- GRU fused + expmap0/proj -> out (templated on OUT dtype) -----
template <typename OT>
__global__ __launch_bounds__(256) void k_gru_f(const bf16* __restrict__ cat, const short* __restrict__ Wc,
                                               const float* __restrict__ bs, const bf16* __restrict__ Hb,
                                               OT* __restrict__ out, int N, const int* flag) {
    if (skip<OT>(flag)) return;
    int wid = threadIdx.x >> 6, lane = threadIdx.x & 63;
    int row0 = blockIdx.x * 64 + wid * 16;
    if (row0 >= N) return;
    int l15 = lane & 15, quad = lane >> 4;
    f32x4 acc[16];
#pragma unroll
    for (int nt = 0; nt < 16; ++nt) acc[nt] = (f32x4){0.f, 0.f, 0.f, 0.f};
    const short* Arow = (const short*)cat + (size_t)(row0 + l15) * 128 + quad * 8;
    for (int k0 = 0; k0 < 128; k0 += 32) {
        short8 a = *(const short8*)(Arow + k0);
#pragma unroll
        for (int nt = 0; nt < 16; ++nt) {
            short8 b = *(const short8*)(Wc + (size_t)(nt * 16 + l15) * 128 + k0 + quad * 8);
            acc[nt] = __builtin_amdgcn_mfma_f32_16x16x32_bf16(a, b, acc[nt], 0, 0, 0);
        }
    }
#pragma unroll
    for (int r = 0; r < 4; ++r) {
        int row = row0 + quad * 4 + r;
        float zv[4], z2 = 0.f;
#pragma unroll
        for (int nt = 0; nt < 4; ++nt) {
            int c = nt * 16 + l15;
            float gr = acc[nt][r] + bs[c];
            float gz = acc[nt + 4][r] + bs[c + 64];
            float gn = acc[nt + 8][r] + bs[c + 128];
            float hn = acc[nt + 12][r] + bs[c + 192];
            float hv = b2f(((const short*)Hb)[(size_t)row * 64 + c]);
            float rr = sigmoidf_(gr), zz = sigmoidf_(gz);
            float nn = tanhf(gn + (rr - 1.f) * hn);
            zv[nt] = (1.f - zz) * nn + zz * hv;
            z2 += zv[nt] * zv[nt];
        }
        z2 = red16(z2);
        float un = fmaxf(sqrtf(z2), MINN);
        float e = tanhf(un), t = e / un;
        float s = (e > MAXN) ? MAXN / e : 1.f;
#pragma unroll
        for (int nt = 0; nt < 4; ++nt)
            st(&out[(size_t)row * 64 + nt * 16 + l15], s * t * zv[nt]);
    }
}

extern "C" void kernel_launch(void* const* d_in, const int* in_sizes, int n_in,
                              void* d_out, int out_size, void* d_ws, size_t ws_size,
                              hipStream_t stream) {
    const int E = in_sizes[0] / 2;
    const int N = in_sizes[1] / 128;
    int win = in_sizes[14] / (N * 64); if (win > 8) win = 8;

    char* wp = (char*)d_ws;
    auto alloc = [&](size_t bytes) -> void* {
        void* p = (void*)wp;
        wp += (bytes + 255) & ~(size_t)255;
        return p;
    };
    bf16* bufA = (bf16*)alloc((size_t)N * 128 * 2);
    bf16* bufB = (bf16*)alloc((size_t)N * 128 * 2);
    bf16* Hbf  = (bf16*)alloc((size_t)N * 64 * 2);
    float* Ebuf = (float*)alloc((size_t)win * N * 4);
    float* Ltb  = (float*)alloc((size_t)win * N * 4);
    float* xnorm = (float*)alloc((size_t)N * 4);
    int* cnt = (int*)alloc((size_t)N * 4);
    int* fillc = (int*)alloc((size_t)N * 4);
    int* rowptr = (int*)alloc((size_t)(N + 1) * 4);
    float* dis = (float*)alloc((size_t)N * 4);
    int* ecol = (int*)alloc((size_t)E * 4);
    float* ew = (float*)alloc((size_t)E * 4);
    int* bsum = (int*)alloc((size_t)1025 * 4);
    float* hb1 = (float*)alloc(128 * 4);
    float* y2a = (float*)alloc(256);
    float* hb2 = (float*)alloc(64 * 4);
    float* y2b = (float*)alloc(256);
    float* blf = (float*)alloc(64 * 4);
    float* bs256 = (float*)alloc(256 * 4);
    float* ratf = (float*)alloc(64 * 4);
    short* QT = (short*)alloc(4096 * 2);
    short* Wc = (short*)alloc((size_t)256 * 128 * 2);
    int* flag = (int*)alloc(256);
    (void)ws_size; (void)out_size; (void)n_in;

    const int* ei = (const int*)d_in[0];

    k_detect<<<1, 256, 0, stream>>>(d_in[14], flag);

    // prep (both dtype variants; non-matching exits immediately)
#define P(T) (const T*)d_in
    k_prep<short><<<1, 256, 0, stream>>>(P(short)[5], P(short)[7], P(short)[3], P(short)[12], P(short)[13],
                                         P(short)[8], P(short)[9], P(short)[10], P(short)[11],
                                         hb1, y2a, hb2, y2b, blf, bs256, ratf, QT, Wc, flag);
    k_prep<float><<<1, 256, 0, stream>>>(P(float)[5], P(float)[7], P(float)[3], P(float)[12], P(float)[13],
                                         P(float)[8], P(float)[9], P(float)[10], P(float)[11],
                                         hb1, y2a, hb2, y2b, blf, bs256, ratf, QT, Wc, flag);
    // CSR build (dtype-free)
    k_zero<<<(N + 255) / 256, 256, 0, stream>>>(cnt, fillc, N);
    k_count<<<(E + 255) / 256, 256, 0, stream>>>(ei, E, cnt);
    {
        int nb = (N + SC_CHUNK - 1) / SC_CHUNK;   // <=1024 for N<=2M
        k_scan_bsum<<<nb, 256, 0, stream>>>(cnt, N, bsum);
        k_scan_bpre<<<1, 1024, 0, stream>>>(bsum, nb);
        k_scan_write<<<nb, 256, 0, stream>>>(cnt, rowptr, N, bsum, nb);
    }
    k_dis<<<(N + 255) / 256, 256, 0, stream>>>(cnt, dis, N);
    k_fill<<<(E + 255) / 256, 256, 0, stream>>>(ei, ei + E, E, rowptr, fillc, ecol, dis, ew);
    // HTA window attention
    int rowsHL = win * N;
    k_att_e<short><<<(rowsHL + 63) / 64, 256, 0, stream>>>(P(short)[14], QT, ratf, Ebuf, Ltb, rowsHL, flag);
    k_att_e<float><<<(rowsHL + 63) / 64, 256, 0, stream>>>(P(float)[14], QT, ratf, Ebuf, Ltb, rowsHL, flag);
    k_att_h<short><<<(N + 3) / 4, 256, 0, stream>>>(Ebuf, Ltb, P(short)[14], Hbf, N, win, flag);
    k_att_h<float><<<(N + 3) / 4, 256, 0, stream>>>(Ebuf, Ltb, P(float)[14], Hbf, N, win, flag);
    // initial linear + toHyperX + concat
    k_lin0<short><<<(N + 63) / 64, 256, 0, stream>>>(P(short)[1], P(short)[2], blf, P(short)[14], win, xnorm, bufA, N, flag);
    k_lin0<float><<<(N + 63) / 64, 256, 0, stream>>>(P(float)[1], P(float)[2], blf, P(float)[14], win, xnorm, bufA, N, flag);
    // conv1
    k_conv_lin<128, short><<<(N + 63) / 64, 256, 0, stream>>>(bufA, P(short)[4], hb1, y2a, xnorm, bufA, N, flag);
    k_conv_lin<128, float><<<(N + 63) / 64, 256, 0, stream>>>(bufA, P(float)[4], hb1, y2a, xnorm, bufA, N, flag);
    k_agg2<<<(N + 3) / 4, 256, 0, stream>>>(bufA, rowptr, ecol, ew, dis, bufB, xnorm, N);
    // conv2
    k_conv_lin<64, short><<<(N + 63) / 64, 256, 0, stream>>>(bufB, P(short)[6], hb2, y2b, xnorm, bufB, N, flag);
    k_conv_lin<64, float><<<(N + 63) / 64, 256, 0, stream>>>(bufB, P(float)[6], hb2, y2b, xnorm, bufB, N, flag);
    k_agg1f<<<(N + 7) / 8, 256, 0, stream>>>(bufB, rowptr, ecol, ew, dis, bufA, Hbf, N);
    // GRU fused + toHyperX -> out (output dtype = detected input dtype)
    k_gru_f<short><<<(N + 63) / 64, 256, 0, stream>>>(bufA, Wc, bs256, Hbf, (short*)d_out, N, flag);
    k_gru_f<float><<<(N + 63) / 64, 256, 0, stream>>>(bufA, Wc, bs256, Hbf, (float*)d_out, N, flag);
#undef P
}

// Round 4
// 807.788 us; speedup vs baseline: 1.5736x; 1.1306x over previous
//
#include <hip/hip_runtime.h>
#include <hip/hip_bf16.h>

typedef __hip_bfloat16 bf16;
typedef __attribute__((ext_vector_type(8))) short short8;
typedef __attribute__((ext_vector_type(4))) float f32x4;
typedef __attribute__((ext_vector_type(4))) unsigned u32x4;

#define MAXN 0.996f      // (1 - 4e-3)/sqrt(c), c=1
#define MINN 1e-15f

__device__ __forceinline__ float b2f(short s) {
    union { unsigned u; float f; } c; c.u = ((unsigned)(unsigned short)s) << 16; return c.f;
}
__device__ __forceinline__ short f2b(float f) {   // RNE bf16
    union { float f; unsigned u; } c; c.f = f;
    unsigned r = c.u + 0x7FFF + ((c.u >> 16) & 1);
    return (short)(r >> 16);
}
__device__ __forceinline__ float lo16f(unsigned u) {
    union { unsigned u; float f; } c; c.u = u << 16; return c.f;
}
__device__ __forceinline__ float hi16f(unsigned u) {
    union { unsigned u; float f; } c; c.u = u & 0xFFFF0000u; return c.f;
}
__device__ __forceinline__ unsigned pk2(float x, float y) {
    return (unsigned)(unsigned short)f2b(x) | ((unsigned)(unsigned short)f2b(y) << 16);
}
__device__ __forceinline__ float cv(short v) { return b2f(v); }
__device__ __forceinline__ float cv(float v) { return v; }
__device__ __forceinline__ short tb(short v) { return v; }
__device__ __forceinline__ short tb(float v) { return f2b(v); }
__device__ __forceinline__ short8 ld8(const short* p) { return *(const short8*)p; }
__device__ __forceinline__ short8 ld8(const float* p) {
    float4 a = *(const float4*)p, b = *(const float4*)(p + 4);
    short8 r;
    r[0] = f2b(a.x); r[1] = f2b(a.y); r[2] = f2b(a.z); r[3] = f2b(a.w);
    r[4] = f2b(b.x); r[5] = f2b(b.y); r[6] = f2b(b.z); r[7] = f2b(b.w);
    return r;
}
__device__ __forceinline__ void ldf8(const short* p, float* f) {
    short8 v = *(const short8*)p;
#pragma unroll
    for (int j = 0; j < 8; ++j) f[j] = b2f(v[j]);
}
__device__ __forceinline__ void ldf8(const float* p, float* f) {
    float4 a = *(const float4*)p, b = *(const float4*)(p + 4);
    f[0] = a.x; f[1] = a.y; f[2] = a.z; f[3] = a.w;
    f[4] = b.x; f[5] = b.y; f[6] = b.z; f[7] = b.w;
}
__device__ __forceinline__ void st(short* p, float v) { *p = f2b(v); }
__device__ __forceinline__ void st(float* p, float v) { *p = v; }

__device__ __forceinline__ float red16(float v) {
#pragma unroll
    for (int m = 1; m < 16; m <<= 1) v += __shfl_xor(v, m);
    return v;
}
__device__ __forceinline__ float red8(float v) {
#pragma unroll
    for (int m = 1; m < 8; m <<= 1) v += __shfl_xor(v, m);
    return v;
}
__device__ __forceinline__ float artanh_(float x) {
    x = fminf(fmaxf(x, -1.f + 1e-7f), 1.f - 1e-7f);
    return 0.5f * (log1pf(x) - log1pf(-x));
}
__device__ __forceinline__ float sigmoidf_(float x) { return 1.f / (1.f + expf(-x)); }

// flag: 0 = storage is bf16, 1 = storage is f32
template <typename T> __device__ __forceinline__ bool skip(const int* flag) {
    return *flag != (int)(sizeof(T) == 4);
}

// ---------------- dtype detector ----------------
__global__ void k_detect(const void* hid, int* flag) {
    const short* p = (const short*)hid;
    int t = threadIdx.x;
    int bad = 0;
    for (int i = t; i < 4096; i += 256) {
        unsigned u = (unsigned)(unsigned short)p[i];
        unsigned ex = (u >> 7) & 0xFF;
        if (ex >= 128) bad = 1;   // |v| >= 2 or NaN/Inf -> cannot be in-ball bf16 data
    }
    __shared__ int s;
    if (t == 0) s = 0;
    __syncthreads();
    if (bad) atomicOr(&s, 1);
    __syncthreads();
    if (t == 0) *flag = s;
}

// ---------------- prep ----------------
template <typename T>
__global__ void k_prep(const T* __restrict__ b1, const T* __restrict__ b2,
                       const T* __restrict__ bl, const T* __restrict__ bih,
                       const T* __restrict__ bhh, const T* __restrict__ Q,
                       const T* __restrict__ ratt, const T* __restrict__ Wih,
                       const T* __restrict__ Whh,
                       float* hb1, float* y2a, float* hb2, float* y2b,
                       float* blf, float* bs256, float* ratf,
                       short* QT, short* Wc, const int* flag) {
    if (skip<T>(flag)) return;
    __shared__ float sb[256];
    int t = threadIdx.x;
    float v1 = (t < 128) ? cv(b1[t]) : 0.f;
    sb[t] = v1 * v1; __syncthreads();
    for (int d = 128; d > 0; d >>= 1) { if (t < d) sb[t] += sb[t + d]; __syncthreads(); }
    float n2a = sb[0]; __syncthreads();
    {
        float un = fmaxf(sqrtf(n2a), MINN);
        float e = tanhf(un), tt = e / un;
        float s = (e > MAXN) ? MAXN / e : 1.f;
        if (t < 128) hb1[t] = s * tt * v1;
        if (t == 0) { float hn = s * e; y2a[0] = hn * hn; }
    }
    float v2 = (t < 64) ? cv(b2[t]) : 0.f;
    sb[t] = v2 * v2; __syncthreads();
    for (int d = 128; d > 0; d >>= 1) { if (t < d) sb[t] += sb[t + d]; __syncthreads(); }
    float n2b = sb[0]; __syncthreads();
    {
        float un = fmaxf(sqrtf(n2b), MINN);
        float e = tanhf(un), tt = e / un;
        float s = (e > MAXN) ? MAXN / e : 1.f;
        if (t < 64) hb2[t] = s * tt * v2;
        if (t == 0) { float hn = s * e; y2b[0] = hn * hn; }
    }
    for (int i = t; i < 64; i += 256) {
        blf[i] = cv(bl[i]);
        ratf[i] = cv(ratt[i]);
    }
    {
        float v = (t < 192) ? (cv(bih[t]) + cv(bhh[t])) : cv(bhh[t - 64]);
        bs256[t] = v;
    }
    for (int i = t; i < 4096; i += 256) { int k = i >> 6, n = i & 63; QT[n * 64 + k] = tb(Q[k * 64 + n]); }
    for (int i = t; i < 256 * 128; i += 256) {
        int d = i >> 7, j = i & 127;
        short v;
        if (d < 192) v = (j < 64) ? tb(Wih[d * 64 + j]) : tb(Whh[d * 64 + (j - 64)]);
        else         v = (j < 64) ? (short)0 : tb(Whh[(d - 64) * 64 + (j - 64)]);
        Wc[i] = v;
    }
}

// ---------------- CSR ----------------
__global__ void k_zero(int* __restrict__ a, int* __restrict__ b, int N) {
    int i = blockIdx.x * blockDim.x + threadIdx.x;
    if (i < N) { a[i] = 0; b[i] = 0; }
}
__global__ void k_count(const int* __restrict__ src, int E, int* __restrict__ cnt) {
    int i = blockIdx.x * blockDim.x + threadIdx.x;
    if (i < E) atomicAdd(&cnt[src[i]], 1);
}

// ---- multi-block exclusive scan ----
#define SC_CHUNK 2048
__global__ __launch_bounds__(256) void k_scan_bsum(const int* __restrict__ cnt, int N,
                                                   int* __restrict__ bsum) {
    __shared__ int sb[256];
    int t = threadIdx.x;
    int base = blockIdx.x * SC_CHUNK + t * 8;
    int s = 0;
#pragma unroll
    for (int j = 0; j < 8; ++j) { int i = base + j; if (i < N) s += cnt[i]; }
    sb[t] = s; __syncthreads();
    for (int d = 128; d > 0; d >>= 1) { if (t < d) sb[t] += sb[t + d]; __syncthreads(); }
    if (t == 0) bsum[blockIdx.x] = sb[0];
}
__global__ __launch_bounds__(1024) void k_scan_bpre(int* __restrict__ bsum, int nb) {
    __shared__ int sb[1024];
    int t = threadIdx.x;
    sb[t] = (t < nb) ? bsum[t] : 0;
    __syncthreads();
    for (int d = 1; d < 1024; d <<= 1) {
        int u = (t >= d) ? sb[t - d] : 0; __syncthreads();
        sb[t] += u; __syncthreads();
    }
    if (t < nb) bsum[t] = (t == 0) ? 0 : sb[t - 1];
    if (t == 0) bsum[nb] = sb[1023];
}
__global__ __launch_bounds__(256) void k_scan_write(const int* __restrict__ cnt,
                                                    int* __restrict__ rowptr, int N,
                                                    const int* __restrict__ bsum, int nb) {
    __shared__ int sb[256];
    int t = threadIdx.x;
    int b = blockIdx.x;
    int base = b * SC_CHUNK + t * 8;
    int v[8]; int s = 0;
#pragma unroll
    for (int j = 0; j < 8; ++j) { int i = base + j; v[j] = (i < N) ? cnt[i] : 0; s += v[j]; }
    sb[t] = s; __syncthreads();
    for (int d = 1; d < 256; d <<= 1) {
        int u = (t >= d) ? sb[t - d] : 0; __syncthreads();
        sb[t] += u; __syncthreads();
    }
    int run = bsum[b] + ((t == 0) ? 0 : sb[t - 1]);
#pragma unroll
    for (int j = 0; j < 8; ++j) {
        int i = base + j;
        if (i < N) rowptr[i] = run;
        run += v[j];
    }
    if (b == 0 && t == 0) rowptr[N] = bsum[nb];
}

__global__ void k_dis(const int* __restrict__ cnt, float* __restrict__ dis, int N) {
    int i = blockIdx.x * blockDim.x + threadIdx.x;
    if (i < N) dis[i] = 1.f / sqrtf((float)(cnt[i] + 1));
}
// fill writes interleaved edge records {col, weight} (weight = dis[s]*dis[d])
__global__ void k_fill(const int* __restrict__ src, const int* __restrict__ dst, int E,
                       const int* __restrict__ rowptr, int* __restrict__ fill,
                       int2* __restrict__ edge, const float* __restrict__ dis) {
    int i = blockIdx.x * blockDim.x + threadIdx.x;
    if (i < E) {
        int s = src[i], d = dst[i];
        int p = rowptr[s] + atomicAdd(&fill[s], 1);
        int2 e; e.x = d; e.y = __float_as_int(dis[s] * dis[d]);
        edge[p] = e;
    }
}

// --------- attention E: fused logmap0 -> (hlog@Q) -> tanh -> @r_att ------
template <typename T>
__global__ __launch_bounds__(256) void k_att_e(const T* __restrict__ hid,
                                               const short* __restrict__ QT,
                                               const float* __restrict__ ratf,
                                               float* __restrict__ Eo,
                                               float* __restrict__ Lt,
                                               int rows, const int* flag) {
    if (skip<T>(flag)) return;
    int wid = threadIdx.x >> 6, lane = threadIdx.x & 63;
    int row0 = blockIdx.x * 64 + wid * 16;
    if (row0 >= rows) return;
    int l15 = lane & 15, quad = lane >> 4;
    const T* Hrow = hid + (size_t)(row0 + l15) * 64 + quad * 8;
    float f0[8], f1[8];
    ldf8(Hrow, f0); ldf8(Hrow + 32, f1);
    float sq = 0.f;
#pragma unroll
    for (int j = 0; j < 8; ++j) sq += f0[j] * f0[j] + f1[j] * f1[j];
    sq += __shfl_xor(sq, 16); sq += __shfl_xor(sq, 32);
    float pn = fmaxf(sqrtf(sq), MINN);
    float lt = artanh_(pn) / pn;
    if (quad == 0) Lt[row0 + l15] = lt;   // cache for k_att_h
    short8 s0, s1;
#pragma unroll
    for (int j = 0; j < 8; ++j) { s0[j] = f2b(lt * f0[j]); s1[j] = f2b(lt * f1[j]); }
    f32x4 acc[4];
#pragma unroll
    for (int nt = 0; nt < 4; ++nt) acc[nt] = (f32x4){0.f, 0.f, 0.f, 0.f};
#pragma unroll
    for (int nt = 0; nt < 4; ++nt) {
        short8 b0 = *(const short8*)(QT + (size_t)(nt * 16 + l15) * 64 + quad * 8);
        short8 b1 = *(const short8*)(QT + (size_t)(nt * 16 + l15) * 64 + 32 + quad * 8);
        acc[nt] = __builtin_amdgcn_mfma_f32_16x16x32_bf16(s0, b0, acc[nt], 0, 0, 0);
        acc[nt] = __builtin_amdgcn_mfma_f32_16x16x32_bf16(s1, b1, acc[nt], 0, 0, 0);
    }
#pragma unroll
    for (int r = 0; r < 4; ++r) {
        float s = 0.f;
#pragma unroll
        for (int nt = 0; nt < 4; ++nt) s += tanhf(acc[nt][r]) * ratf[nt * 16 + l15];
        s = red16(s);
        if (l15 == 0) Eo[row0 + quad * 4 + r] = s;
    }
}

// --------- attention combine: softmax over window, h = mean(a*hlog) -----
template <typename T>
__global__ __launch_bounds__(256) void k_att_h(const float* __restrict__ Eb,
                                               const float* __restrict__ Lt,
                                               const T* __restrict__ hid,
                                               bf16* __restrict__ Hb, int N, int win, const int* flag) {
    if (skip<T>(flag)) return;
    int wid = threadIdx.x >> 6, lane = threadIdx.x & 63;
    int i = blockIdx.x * 4 + wid;
    if (i >= N) return;
    float hl[8], ev[8];
    float m = -1e30f;
    for (int w = 0; w < win; ++w) {
        float p = cv(hid[((size_t)w * N + i) * 64 + lane]);
        hl[w] = Lt[(size_t)w * N + i] * p;
        ev[w] = Eb[(size_t)w * N + i];
        m = fmaxf(m, ev[w]);
    }
    float s = 0.f;
    for (int w = 0; w < win; ++w) { ev[w] = expf(ev[w] - m); s += ev[w]; }
    float h = 0.f;
    for (int w = 0; w < win; ++w) h += ev[w] * hl[w];
    ((short*)Hb)[(size_t)i * 64 + lane] = f2b(h / (s * (float)win));
}

// --------- initial linear + expmap0/proj + concat hidden + proj128 ------
template <typename T>
__global__ __launch_bounds__(256) void k_lin0(const T* __restrict__ feat, const T* __restrict__ Wl,
                                              const float* __restrict__ blf, const T* __restrict__ hid,
                                              int win, float* __restrict__ xnorm,
                                              bf16* __restrict__ outA, int N, const int* flag) {
    if (skip<T>(flag)) return;
    int wid = threadIdx.x >> 6, lane = threadIdx.x & 63;
    int row0 = blockIdx.x * 64 + wid * 16;
    if (row0 >= N) return;
    int l15 = lane & 15, quad = lane >> 4;
    f32x4 acc[4];
#pragma unroll
    for (int nt = 0; nt < 4; ++nt) acc[nt] = (f32x4){0.f, 0.f, 0.f, 0.f};
    const T* Arow = feat + (size_t)(row0 + l15) * 128 + quad * 8;
    for (int k0 = 0; k0 < 128; k0 += 32) {
        short8 a = ld8(Arow + k0);
#pragma unroll
        for (int nt = 0; nt < 4; ++nt) {
            short8 b = ld8(Wl + (size_t)(nt * 16 + l15) * 128 + k0 + quad * 8);
            acc[nt] = __builtin_amdgcn_mfma_f32_16x16x32_bf16(a, b, acc[nt], 0, 0, 0);
        }
    }
    float bv[4];
#pragma unroll
    for (int nt = 0; nt < 4; ++nt) bv[nt] = blf[nt * 16 + l15];
#pragma unroll
    for (int r = 0; r < 4; ++r) {
        int row = row0 + quad * 4 + r;
        float g[4], u2 = 0.f;
#pragma unroll
        for (int nt = 0; nt < 4; ++nt) { g[nt] = acc[nt][r] + bv[nt]; u2 += g[nt] * g[nt]; }
        u2 = red16(u2);
        float un = fmaxf(sqrtf(u2), MINN);
        float e = tanhf(un), t = e / un;
        float s1 = (e > MAXN) ? MAXN / e : 1.f;
        float x0n = s1 * e;
        float hv[4], h2 = 0.f;
#pragma unroll
        for (int nt = 0; nt < 4; ++nt) {
            hv[nt] = cv(hid[((size_t)(win - 1) * N + row) * 64 + nt * 16 + l15]);
            h2 += hv[nt] * hv[nt];
        }
        h2 = red16(h2);
        float n128 = sqrtf(x0n * x0n + h2);
        float s2 = (n128 > MAXN) ? MAXN / n128 : 1.f;
#pragma unroll
        for (int nt = 0; nt < 4; ++nt) {
            ((short*)outA)[(size_t)row * 128 + nt * 16 + l15] = f2b(s2 * s1 * t * g[nt]);
            ((short*)outA)[(size_t)row * 128 + 64 + nt * 16 + l15] = f2b(s2 * hv[nt]);
        }
        if (l15 == 0) xnorm[row] = fmaxf(fminf(n128, MAXN), MINN);
    }
}

// ------- conv linear: GEMM fused with matvec->proj->madd(hb)->proj->logmap0 ----
template <int DOUT, typename T>
__global__ __launch_bounds__(256) void k_conv_lin(const bf16* __restrict__ in, const T* __restrict__ W,
                                                  const float* __restrict__ hb, const float* __restrict__ y2p,
                                                  const float* __restrict__ xnorm,
                                                  bf16* __restrict__ out, int N, const int* flag) {
    if (skip<T>(flag)) return;
    constexpr int NT = DOUT / 16;
    int wid = threadIdx.x >> 6, lane = threadIdx.x & 63;
    int row0 = blockIdx.x * 64 + wid * 16;
    if (row0 >= N) return;
    int l15 = lane & 15, quad = lane >> 4;
    f32x4 acc[NT];
#pragma unroll
    for (int nt = 0; nt < NT; ++nt) acc[nt] = (f32x4){0.f, 0.f, 0.f, 0.f};
    const short* Arow = (const short*)in + (size_t)(row0 + l15) * 128 + quad * 8;
    for (int k0 = 0; k0 < 128; k0 += 32) {
        short8 a = *(const short8*)(Arow + k0);
#pragma unroll
        for (int nt = 0; nt < NT; ++nt) {
            short8 b = ld8(W + (size_t)(nt * 16 + l15) * 128 + k0 + quad * 8);
            acc[nt] = __builtin_amdgcn_mfma_f32_16x16x32_bf16(a, b, acc[nt], 0, 0, 0);
        }
    }
    float y2 = y2p[0];
    float hbv[NT];
#pragma unroll
    for (int nt = 0; nt < NT; ++nt) hbv[nt] = hb[nt * 16 + l15];
#pragma unroll
    for (int r = 0; r < 4; ++r) {
        int row = row0 + quad * 4 + r;
        float mx[NT], m2 = 0.f;
#pragma unroll
        for (int nt = 0; nt < NT; ++nt) { mx[nt] = acc[nt][r]; m2 += mx[nt] * mx[nt]; }
        m2 = red16(m2);
        float mxn = fmaxf(sqrtf(m2), MINN);
        float xn = xnorm[row];
        float at = artanh_(xn);
        float f = (m2 == 0.f) ? 0.f : tanhf(mxn / xn * at) / mxn;
        float rn = f * mxn;
        float s1 = (rn > MAXN) ? MAXN / rn : 1.f;
        float a_ = s1 * f, mvn = s1 * rn;
        float x2 = mvn * mvn;
        float xy = 0.f;
#pragma unroll
    for (int nt = 0; nt < NT; ++nt) xy += (a_ * mx[nt]) * hbv[nt];
        xy = red16(xy);
        float co = 1.f + 2.f * xy + y2, cx = 1.f - x2;
        float den = fmaxf(1.f + 2.f * xy + x2 * y2, MINN);
        float o[NT], on2 = 0.f;
#pragma unroll
        for (int nt = 0; nt < NT; ++nt) { o[nt] = (co * a_ * mx[nt] + cx * hbv[nt]) / den; on2 += o[nt] * o[nt]; }
        on2 = red16(on2);
        float on = sqrtf(on2);
        float s3 = (on > MAXN) ? MAXN / on : 1.f;
        float hn = fmaxf(s3 * on, MINN);
        float lt = artanh_(hn) / hn;
#pragma unroll
        for (int nt = 0; nt < NT; ++nt)
            ((short*)out)[(size_t)row * 128 + nt * 16 + l15] = f2b(lt * s3 * o[nt]);
    }
}

// --------- agg (conv1, D=128): 4 nodes/wave, 16 lanes/node, dwordx4 -------
__global__ __launch_bounds__(256) void k_agg2(const bf16* __restrict__ xt, const int* __restrict__ rowptr,
                                              const int2* __restrict__ edge,
                                              const float* __restrict__ dis,
                                              bf16* __restrict__ out, float* __restrict__ xnorm, int N) {
    int wid = threadIdx.x >> 6, lane = threadIdx.x & 63;
    int g = lane >> 4, l15 = lane & 15;
    int i = blockIdx.x * 16 + wid * 4 + g;
    bool act = (i < N);
    int ii = act ? i : (N - 1);
    const u32x4* xq = (const u32x4*)xt;            // 16 u32x4 per 128-feat row
    float di = dis[ii];
    float w0 = di * di;
    u32x4 d0 = xq[(size_t)ii * 16 + l15];
    float a[8];
#pragma unroll
    for (int k = 0; k < 4; ++k) { a[2 * k] = w0 * lo16f(d0[k]); a[2 * k + 1] = w0 * hi16f(d0[k]); }
    int e0 = rowptr[ii], e1 = act ? rowptr[ii + 1] : e0;
    for (int j = e0; j < e1; ++j) {
        int2 e = edge[j];
        float w = __int_as_float(e.y);
        u32x4 d = xq[(size_t)e.x * 16 + l15];
#pragma unroll
        for (int k = 0; k < 4; ++k) { a[2 * k] += w * lo16f(d[k]); a[2 * k + 1] += w * hi16f(d[k]); }
    }
    float sq = 0.f;
#pragma unroll
    for (int k = 0; k < 8; ++k) sq += a[k] * a[k];
    float an = fmaxf(sqrtf(red16(sq)), MINN);
    float e1t = tanhf(an), t1 = e1t / an;
    float s1 = (e1t > MAXN) ? MAXN / e1t : 1.f;
    float hn = fmaxf(s1 * e1t, MINN);
    float lt = artanh_(hn) / hn;
    float sht = s1 * t1 * lt;
    float v[8], v2 = 0.f;
#pragma unroll
    for (int k = 0; k < 8; ++k) {
        float t = sht * a[k];
        t = (t >= 0.f) ? t : 0.01f * t;
        v[k] = t; v2 += t * t;
    }
    float tn = fmaxf(sqrtf(red16(v2)), MINN);
    float e2 = tanhf(tn), t2 = e2 / tn;
    float s2 = (e2 > MAXN) ? MAXN / e2 : 1.f;
    float sc = s2 * t2;
    if (act) {
        u32x4 o;
#pragma unroll
        for (int k = 0; k < 4; ++k) o[k] = pk2(sc * v[2 * k], sc * v[2 * k + 1]);
        ((u32x4*)out)[(size_t)i * 16 + l15] = o;
        if (l15 == 0) xnorm[i] = fmaxf(fminf(e2, MAXN), MINN);
    }
}

// --------- agg (conv2, D=64) + FINAL logmap0: 8 nodes/wave, 8 lanes/node --
__global__ __launch_bounds__(256) void k_agg1f(const bf16* __restrict__ xt, const int* __restrict__ rowptr,
                                               const int2* __restrict__ edge,
                                               const float* __restrict__ dis,
                                               bf16* __restrict__ out, const bf16* __restrict__ Hb, int N) {
    int wid = threadIdx.x >> 6, lane = threadIdx.x & 63;
    int g = lane >> 3, l7 = lane & 7;
    int i = blockIdx.x * 32 + wid * 8 + g;
    bool act = (i < N);
    int ii = act ? i : (N - 1);
    const u32x4* xq = (const u32x4*)xt;            // row stride 16 u32x4; feats = first 8
    float di = dis[ii];
    float w0 = di * di;
    u32x4 d0 = xq[(size_t)ii * 16 + l7];
    float a[8];
#pragma unroll
    for (int k = 0; k < 4; ++k) { a[2 * k] = w0 * lo16f(d0[k]); a[2 * k + 1] = w0 * hi16f(d0[k]); }
    int e0 = rowptr[ii], e1 = act ? rowptr[ii + 1] : e0;
    for (int j = e0; j < e1; ++j) {
        int2 e = edge[j];
        float w = __int_as_float(e.y);
        u32x4 d = xq[(size_t)e.x * 16 + l7];
#pragma unroll
        for (int k = 0; k < 4; ++k) { a[2 * k] += w * lo16f(d[k]); a[2 * k + 1] += w * hi16f(d[k]); }
    }
    float sq = 0.f;
#pragma unroll
    for (int k = 0; k < 8; ++k) sq += a[k] * a[k];
    float an = fmaxf(sqrtf(red8(sq)), MINN);
    float e1t = tanhf(an), t1 = e1t / an;
    float s1 = (e1t > MAXN) ? MAXN / e1t : 1.f;
    float hn = fmaxf(s1 * e1t, MINN);
    float lt = artanh_(hn) / hn;
    float sht = s1 * t1 * lt;
    float v[8], v2 = 0.f;
#pragma unroll
    for (int k = 0; k < 8; ++k) {
        float t = sht * a[k];
        t = (t >= 0.f) ? t : 0.01f * t;
        v[k] = t; v2 += t * t;
    }
    float tn = fmaxf(sqrtf(red8(v2)), MINN);
    float e2 = tanhf(tn), t2 = e2 / tn;
    float s2 = (e2 > MAXN) ? MAXN / e2 : 1.f;
    float sc = s2 * t2;
    float xnf = fmaxf(fminf(s2 * e2, MAXN), MINN);
    float lt2 = artanh_(xnf) / xnf;
    sc *= lt2;
    if (act) {
        u32x4 o;
#pragma unroll
        for (int k = 0; k < 4; ++k) o[k] = pk2(sc * v[2 * k], sc * v[2 * k + 1]);
        u32x4* od = (u32x4*)out;
        od[(size_t)i * 16 + l7] = o;
        od[(size_t)i * 16 + 8 + l7] = ((const u32x4*)Hb)[(size_t)i * 8 + l7];
    }
}

// --------- GRU fused + expmap0/proj -> out (templated on OUT dtype) -----
template <typename OT>
__global__ __launch_bounds__(256) void k_gru_f(const bf16* __restrict__ cat, const short* __restrict__ Wc,
                                               const float* __restrict__ bs, const bf16* __restrict__ Hb,
                                               OT* __restrict__ out, int N, const int* flag) {
    if (skip<OT>(flag)) return;
    int wid = threadIdx.x >> 6, lane = threadIdx.x & 63;
    int row0 = blockIdx.x * 64 + wid * 16;
    if (row0 >= N) return;
    int l15 = lane & 15, quad = lane >> 4;
    f32x4 acc[16];
#pragma unroll
    for (int nt = 0; nt < 16; ++nt) acc[nt] = (f32x4){0.f, 0.f, 0.f, 0.f};
    const short* Arow = (const short*)cat + (size_t)(row0 + l15) * 128 + quad * 8;
    for (int k0 = 0; k0 < 128; k0 += 32) {
        short8 a = *(const short8*)(Arow + k0);
#pragma unroll
        for (int nt = 0; nt < 16; ++nt) {
            short8 b = *(const short8*)(Wc + (size_t)(nt * 16 + l15) * 128 + k0 + quad * 8);
            acc[nt] = __builtin_amdgcn_mfma_f32_16x16x32_bf16(a, b, acc[nt], 0, 0, 0);
        }
    }
#pragma unroll
    for (int r = 0; r < 4; ++r) {
        int row = row0 + quad * 4 + r;
        float zv[4], z2 = 0.f;
#pragma unroll
        for (int nt = 0; nt < 4; ++nt) {
            int c = nt * 16 + l15;
            float gr = acc[nt][r] + bs[c];
            float gz = acc[nt + 4][r] + bs[c + 64];
            float gn = acc[nt + 8][r] + bs[c + 128];
            float hn = acc[nt + 12][r] + bs[c + 192];
            float hv = b2f(((const short*)Hb)[(size_t)row * 64 + c]);
            float rr = sigmoidf_(gr), zz = sigmoidf_(gz);
            float nn = tanhf(gn + (rr - 1.f) * hn);
            zv[nt] = (1.f - zz) * nn + zz * hv;
            z2 += zv[nt] * zv[nt];
        }
        z2 = red16(z2);
        float un = fmaxf(sqrtf(z2), MINN);
        float e = tanhf(un), t = e / un;
        float s = (e > MAXN) ? MAXN / e : 1.f;
#pragma unroll
        for (int nt = 0; nt < 4; ++nt)
            st(&out[(size_t)row * 64 + nt * 16 + l15], s * t * zv[nt]);
    }
}

extern "C" void kernel_launch(void* const* d_in, const int* in_sizes, int n_in,
                              void* d_out, int out_size, void* d_ws, size_t ws_size,
                              hipStream_t stream) {
    const int E = in_sizes[0] / 2;
    const int N = in_sizes[1] / 128;
    int win = in_sizes[14] / (N * 64); if (win > 8) win = 8;

    char* wp = (char*)d_ws;
    auto alloc = [&](size_t bytes) -> void* {
        void* p = (void*)wp;
        wp += (bytes + 255) & ~(size_t)255;
        return p;
    };
    bf16* bufA = (bf16*)alloc((size_t)N * 128 * 2);
    bf16* bufB = (bf16*)alloc((size_t)N * 128 * 2);
    bf16* Hbf  = (bf16*)alloc((size_t)N * 64 * 2);
    float* Ebuf = (float*)alloc((size_t)win * N * 4);
    float* Ltb  = (float*)alloc((size_t)win * N * 4);
    float* xnorm = (float*)alloc((size_t)N * 4);
    int* cnt = (int*)alloc((size_t)N * 4);
    int* fillc = (int*)alloc((size_t)N * 4);
    int* rowptr = (int*)alloc((size_t)(N + 1) * 4);
    float* dis = (float*)alloc((size_t)N * 4);
    int2* edge = (int2*)alloc((size_t)E * 8);
    int* bsum = (int*)alloc((size_t)1025 * 4);
    float* hb1 = (float*)alloc(128 * 4);
    float* y2a = (float*)alloc(256);
    float* hb2 = (float*)alloc(64 * 4);
    float* y2b = (float*)alloc(256);
    float* blf = (float*)alloc(64 * 4);
    float* bs256 = (float*)alloc(256 * 4);
    float* ratf = (float*)alloc(64 * 4);
    short* QT = (short*)alloc(4096 * 2);
    short* Wc = (short*)alloc((size_t)256 * 128 * 2);
    int* flag = (int*)alloc(256);
    (void)ws_size; (void)out_size; (void)n_in;

    const int* ei = (const int*)d_in[0];

    k_detect<<<1, 256, 0, stream>>>(d_in[14], flag);

    // prep (both dtype variants; non-matching exits immediately)
#define P(T) (const T*)d_in
    k_prep<short><<<1, 256, 0, stream>>>(P(short)[5], P(short)[7], P(short)[3], P(short)[12], P(short)[13],
                                         P(short)[8], P(short)[9], P(short)[10], P(short)[11],
                                         hb1, y2a, hb2, y2b, blf, bs256, ratf, QT, Wc, flag);
    k_prep<float><<<1, 256, 0, stream>>>(P(float)[5], P(float)[7], P(float)[3], P(float)[12], P(float)[13],
                                         P(float)[8], P(float)[9], P(float)[10], P(float)[11],
                                         hb1, y2a, hb2, y2b, blf, bs256, ratf, QT, Wc, flag);
    // CSR build (dtype-free)
    k_zero<<<(N + 255) / 256, 256, 0, stream>>>(cnt, fillc, N);
    k_count<<<(E + 255) / 256, 256, 0, stream>>>(ei, E, cnt);
    {
        int nb = (N + SC_CHUNK - 1) / SC_CHUNK;   // <=1024 for N<=2M
        k_scan_bsum<<<nb, 256, 0, stream>>>(cnt, N, bsum);
        k_scan_bpre<<<1, 1024, 0, stream>>>(bsum, nb);
        k_scan_write<<<nb, 256, 0, stream>>>(cnt, rowptr, N, bsum, nb);
    }
    k_dis<<<(N + 255) / 256, 256, 0, stream>>>(cnt, dis, N);
    k_fill<<<(E + 255) / 256, 256, 0, stream>>>(ei, ei + E, E, rowptr, fillc, edge, dis);
    // HTA window attention
    int rowsHL = win * N;
    k_att_e<short><<<(rowsHL + 63) / 64, 256, 0, stream>>>(P(short)[14], QT, ratf, Ebuf, Ltb, rowsHL, flag);
    k_att_e<float><<<(rowsHL + 63) / 64, 256, 0, stream>>>(P(float)[14], QT, ratf, Ebuf, Ltb, rowsHL, flag);
    k_att_h<short><<<(N + 3) / 4, 256, 0, stream>>>(Ebuf, Ltb, P(short)[14], Hbf, N, win, flag);
    k_att_h<float><<<(N + 3) / 4, 256, 0, stream>>>(Ebuf, Ltb, P(float)[14], Hbf, N, win, flag);
    // initial linear + toHyperX + concat
    k_lin0<short><<<(N + 63) / 64, 256, 0, stream>>>(P(short)[1], P(short)[2], blf, P(short)[14], win, xnorm, bufA, N, flag);
    k_lin0<float><<<(N + 63) / 64, 256, 0, stream>>>(P(float)[1], P(float)[2], blf, P(float)[14], win, xnorm, bufA, N, flag);
    // conv1
    k_conv_lin<128, short><<<(N + 63) / 64, 256, 0, stream>>>(bufA, P(short)[4], hb1, y2a, xnorm, bufA, N, flag);
    k_conv_lin<128, float><<<(N + 63) / 64, 256, 0, stream>>>(bufA, P(float)[4], hb1, y2a, xnorm, bufA, N, flag);
    k_agg2<<<(N + 15) / 16, 256, 0, stream>>>(bufA, rowptr, edge, dis, bufB, xnorm, N);
    // conv2
    k_conv_lin<64, short><<<(N + 63) / 64, 256, 0, stream>>>(bufB, P(short)[6], hb2, y2b, xnorm, bufB, N, flag);
    k_conv_lin<64, float><<<(N + 63) / 64, 256, 0, stream>>>(bufB, P(float)[6], hb2, y2b, xnorm, bufB, N, flag);
    k_agg1f<<<(N + 31) / 32, 256, 0, stream>>>(bufB, rowptr, edge, dis, bufA, Hbf, N);
    // GRU fused + toHyperX -> out (output dtype = detected input dtype)
    k_gru_f<short><<<(N + 63) / 64, 256, 0, stream>>>(bufA, Wc, bs256, Hbf, (short*)d_out, N, flag);
    k_gru_f<float><<<(N + 63) / 64, 256, 0, stream>>>(bufA, Wc, bs256, Hbf, (float*)d_out, N, flag);
#undef P
}

// Round 5
// 765.718 us; speedup vs baseline: 1.6600x; 1.0549x over previous
//
#include <hip/hip_runtime.h>
#include <hip/hip_bf16.h>

typedef __hip_bfloat16 bf16;
typedef __attribute__((ext_vector_type(8))) short short8;
typedef __attribute__((ext_vector_type(4))) float f32x4;
typedef __attribute__((ext_vector_type(4))) unsigned u32x4;

#define MAXN 0.996f      // (1 - 4e-3)/sqrt(c), c=1
#define MINN 1e-15f

__device__ __forceinline__ float b2f(short s) {
    union { unsigned u; float f; } c; c.u = ((unsigned)(unsigned short)s) << 16; return c.f;
}
__device__ __forceinline__ short f2b(float f) {   // RNE bf16
    union { float f; unsigned u; } c; c.f = f;
    unsigned r = c.u + 0x7FFF + ((c.u >> 16) & 1);
    return (short)(r >> 16);
}
__device__ __forceinline__ float lo16f(unsigned u) {
    union { unsigned u; float f; } c; c.u = u << 16; return c.f;
}
__device__ __forceinline__ float hi16f(unsigned u) {
    union { unsigned u; float f; } c; c.u = u & 0xFFFF0000u; return c.f;
}
__device__ __forceinline__ unsigned pk2(float x, float y) {
    return (unsigned)(unsigned short)f2b(x) | ((unsigned)(unsigned short)f2b(y) << 16);
}
__device__ __forceinline__ float cv(short v) { return b2f(v); }
__device__ __forceinline__ float cv(float v) { return v; }
__device__ __forceinline__ short tb(short v) { return v; }
__device__ __forceinline__ short tb(float v) { return f2b(v); }
__device__ __forceinline__ short8 ld8(const short* p) { return *(const short8*)p; }
__device__ __forceinline__ short8 ld8(const float* p) {
    float4 a = *(const float4*)p, b = *(const float4*)(p + 4);
    short8 r;
    r[0] = f2b(a.x); r[1] = f2b(a.y); r[2] = f2b(a.z); r[3] = f2b(a.w);
    r[4] = f2b(b.x); r[5] = f2b(b.y); r[6] = f2b(b.z); r[7] = f2b(b.w);
    return r;
}
__device__ __forceinline__ void ldf8(const short* p, float* f) {
    short8 v = *(const short8*)p;
#pragma unroll
    for (int j = 0; j < 8; ++j) f[j] = b2f(v[j]);
}
__device__ __forceinline__ void ldf8(const float* p, float* f) {
    float4 a = *(const float4*)p, b = *(const float4*)(p + 4);
    f[0] = a.x; f[1] = a.y; f[2] = a.z; f[3] = a.w;
    f[4] = b.x; f[5] = b.y; f[6] = b.z; f[7] = b.w;
}
__device__ __forceinline__ void st(short* p, float v) { *p = f2b(v); }
__device__ __forceinline__ void st(float* p, float v) { *p = v; }

__device__ __forceinline__ float red16(float v) {
#pragma unroll
    for (int m = 1; m < 16; m <<= 1) v += __shfl_xor(v, m);
    return v;
}
__device__ __forceinline__ float red8(float v) {
#pragma unroll
    for (int m = 1; m < 8; m <<= 1) v += __shfl_xor(v, m);
    return v;
}
__device__ __forceinline__ float artanh_(float x) {
    x = fminf(fmaxf(x, -1.f + 1e-7f), 1.f - 1e-7f);
    return 0.5f * (log1pf(x) - log1pf(-x));
}
__device__ __forceinline__ float sigmoidf_(float x) { return 1.f / (1.f + expf(-x)); }

// flag: 0 = storage is bf16, 1 = storage is f32
template <typename T> __device__ __forceinline__ bool skip(const int* flag) {
    return *flag != (int)(sizeof(T) == 4);
}

// ---------------- dtype detector ----------------
__global__ void k_detect(const void* hid, int* flag) {
    const short* p = (const short*)hid;
    int t = threadIdx.x;
    int bad = 0;
    for (int i = t; i < 4096; i += 256) {
        unsigned u = (unsigned)(unsigned short)p[i];
        unsigned ex = (u >> 7) & 0xFF;
        if (ex >= 128) bad = 1;   // |v| >= 2 or NaN/Inf -> cannot be in-ball bf16 data
    }
    __shared__ int s;
    if (t == 0) s = 0;
    __syncthreads();
    if (bad) atomicOr(&s, 1);
    __syncthreads();
    if (t == 0) *flag = s;
}

// ---------------- prep ----------------
template <typename T>
__global__ void k_prep(const T* __restrict__ b1, const T* __restrict__ b2,
                       const T* __restrict__ bl, const T* __restrict__ bih,
                       const T* __restrict__ bhh, const T* __restrict__ Q,
                       const T* __restrict__ ratt, const T* __restrict__ Wih,
                       const T* __restrict__ Whh,
                       float* hb1, float* y2a, float* hb2, float* y2b,
                       float* blf, float* bs256, float* ratf,
                       short* QT, short* Wc, const int* flag) {
    if (skip<T>(flag)) return;
    __shared__ float sb[256];
    int t = threadIdx.x;
    float v1 = (t < 128) ? cv(b1[t]) : 0.f;
    sb[t] = v1 * v1; __syncthreads();
    for (int d = 128; d > 0; d >>= 1) { if (t < d) sb[t] += sb[t + d]; __syncthreads(); }
    float n2a = sb[0]; __syncthreads();
    {
        float un = fmaxf(sqrtf(n2a), MINN);
        float e = tanhf(un), tt = e / un;
        float s = (e > MAXN) ? MAXN / e : 1.f;
        if (t < 128) hb1[t] = s * tt * v1;
        if (t == 0) { float hn = s * e; y2a[0] = hn * hn; }
    }
    float v2 = (t < 64) ? cv(b2[t]) : 0.f;
    sb[t] = v2 * v2; __syncthreads();
    for (int d = 128; d > 0; d >>= 1) { if (t < d) sb[t] += sb[t + d]; __syncthreads(); }
    float n2b = sb[0]; __syncthreads();
    {
        float un = fmaxf(sqrtf(n2b), MINN);
        float e = tanhf(un), tt = e / un;
        float s = (e > MAXN) ? MAXN / e : 1.f;
        if (t < 64) hb2[t] = s * tt * v2;
        if (t == 0) { float hn = s * e; y2b[0] = hn * hn; }
    }
    for (int i = t; i < 64; i += 256) {
        blf[i] = cv(bl[i]);
        ratf[i] = cv(ratt[i]);
    }
    {
        float v = (t < 192) ? (cv(bih[t]) + cv(bhh[t])) : cv(bhh[t - 64]);
        bs256[t] = v;
    }
    for (int i = t; i < 4096; i += 256) { int k = i >> 6, n = i & 63; QT[n * 64 + k] = tb(Q[k * 64 + n]); }
    for (int i = t; i < 256 * 128; i += 256) {
        int d = i >> 7, j = i & 127;
        short v;
        if (d < 192) v = (j < 64) ? tb(Wih[d * 64 + j]) : tb(Whh[d * 64 + (j - 64)]);
        else         v = (j < 64) ? (short)0 : tb(Whh[(d - 64) * 64 + (j - 64)]);
        Wc[i] = v;
    }
}

// ---- weight pre-conversion: Wl(64x128), W1(128x128), W2(64x128) -> bf16 ----
template <typename T>
__global__ __launch_bounds__(256) void k_wcvt(const T* __restrict__ Wl, const T* __restrict__ W1,
                                              const T* __restrict__ W2,
                                              short* __restrict__ Wlb, short* __restrict__ W1b,
                                              short* __restrict__ W2b, const int* flag) {
    if (skip<T>(flag)) return;
    int i = blockIdx.x * 256 + threadIdx.x;
    if (i < 8192) Wlb[i] = tb(Wl[i]);
    else if (i < 24576) W1b[i - 8192] = tb(W1[i - 8192]);
    else if (i < 32768) W2b[i - 24576] = tb(W2[i - 24576]);
}

// ---------------- CSR ----------------
__global__ void k_zero(int* __restrict__ a, int* __restrict__ b, int N) {
    int i = blockIdx.x * blockDim.x + threadIdx.x;
    if (i < N) { a[i] = 0; b[i] = 0; }
}
__global__ void k_count(const int* __restrict__ src, int E, int* __restrict__ cnt) {
    int i = blockIdx.x * blockDim.x + threadIdx.x;
    if (i < E) atomicAdd(&cnt[src[i]], 1);
}

// ---- multi-block exclusive scan ----
#define SC_CHUNK 2048
__global__ __launch_bounds__(256) void k_scan_bsum(const int* __restrict__ cnt, int N,
                                                   int* __restrict__ bsum) {
    __shared__ int sb[256];
    int t = threadIdx.x;
    int base = blockIdx.x * SC_CHUNK + t * 8;
    int s = 0;
#pragma unroll
    for (int j = 0; j < 8; ++j) { int i = base + j; if (i < N) s += cnt[i]; }
    sb[t] = s; __syncthreads();
    for (int d = 128; d > 0; d >>= 1) { if (t < d) sb[t] += sb[t + d]; __syncthreads(); }
    if (t == 0) bsum[blockIdx.x] = sb[0];
}
__global__ __launch_bounds__(1024) void k_scan_bpre(int* __restrict__ bsum, int nb) {
    __shared__ int sb[1024];
    int t = threadIdx.x;
    sb[t] = (t < nb) ? bsum[t] : 0;
    __syncthreads();
    for (int d = 1; d < 1024; d <<= 1) {
        int u = (t >= d) ? sb[t - d] : 0; __syncthreads();
        sb[t] += u; __syncthreads();
    }
    if (t < nb) bsum[t] = (t == 0) ? 0 : sb[t - 1];
    if (t == 0) bsum[nb] = sb[1023];
}
__global__ __launch_bounds__(256) void k_scan_write(const int* __restrict__ cnt,
                                                    int* __restrict__ rowptr, int N,
                                                    const int* __restrict__ bsum, int nb) {
    __shared__ int sb[256];
    int t = threadIdx.x;
    int b = blockIdx.x;
    int base = b * SC_CHUNK + t * 8;
    int v[8]; int s = 0;
#pragma unroll
    for (int j = 0; j < 8; ++j) { int i = base + j; v[j] = (i < N) ? cnt[i] : 0; s += v[j]; }
    sb[t] = s; __syncthreads();
    for (int d = 1; d < 256; d <<= 1) {
        int u = (t >= d) ? sb[t - d] : 0; __syncthreads();
        sb[t] += u; __syncthreads();
    }
    int run = bsum[b] + ((t == 0) ? 0 : sb[t - 1]);
#pragma unroll
    for (int j = 0; j < 8; ++j) {
        int i = base + j;
        if (i < N) rowptr[i] = run;
        run += v[j];
    }
    if (b == 0 && t == 0) rowptr[N] = bsum[nb];
}

__global__ void k_dis(const int* __restrict__ cnt, float* __restrict__ dis, int N) {
    int i = blockIdx.x * blockDim.x + threadIdx.x;
    if (i < N) dis[i] = 1.f / sqrtf((float)(cnt[i] + 1));
}
// fill writes interleaved edge records {col, weight} (weight = dis[s]*dis[d])
__global__ void k_fill(const int* __restrict__ src, const int* __restrict__ dst, int E,
                       const int* __restrict__ rowptr, int* __restrict__ fill,
                       int2* __restrict__ edge, const float* __restrict__ dis) {
    int i = blockIdx.x * blockDim.x + threadIdx.x;
    if (i < E) {
        int s = src[i], d = dst[i];
        int p = rowptr[s] + atomicAdd(&fill[s], 1);
        int2 e; e.x = d; e.y = __float_as_int(dis[s] * dis[d]);
        edge[p] = e;
    }
}

// --------- attention E: fused logmap0 -> (hlog@Q) -> tanh -> @r_att ------
template <typename T>
__global__ __launch_bounds__(256) void k_att_e(const T* __restrict__ hid,
                                               const short* __restrict__ QT,
                                               const float* __restrict__ ratf,
                                               float* __restrict__ Eo,
                                               float* __restrict__ Lt,
                                               int rows, const int* flag) {
    if (skip<T>(flag)) return;
    int wid = threadIdx.x >> 6, lane = threadIdx.x & 63;
    int row0 = blockIdx.x * 64 + wid * 16;
    if (row0 >= rows) return;
    int l15 = lane & 15, quad = lane >> 4;
    const T* Hrow = hid + (size_t)(row0 + l15) * 64 + quad * 8;
    float f0[8], f1[8];
    ldf8(Hrow, f0); ldf8(Hrow + 32, f1);
    float sq = 0.f;
#pragma unroll
    for (int j = 0; j < 8; ++j) sq += f0[j] * f0[j] + f1[j] * f1[j];
    sq += __shfl_xor(sq, 16); sq += __shfl_xor(sq, 32);
    float pn = fmaxf(sqrtf(sq), MINN);
    float lt = artanh_(pn) / pn;
    if (quad == 0) Lt[row0 + l15] = lt;   // cache for k_att_h
    short8 s0, s1;
#pragma unroll
    for (int j = 0; j < 8; ++j) { s0[j] = f2b(lt * f0[j]); s1[j] = f2b(lt * f1[j]); }
    f32x4 acc[4];
#pragma unroll
    for (int nt = 0; nt < 4; ++nt) acc[nt] = (f32x4){0.f, 0.f, 0.f, 0.f};
#pragma unroll
    for (int nt = 0; nt < 4; ++nt) {
        short8 b0 = *(const short8*)(QT + (size_t)(nt * 16 + l15) * 64 + quad * 8);
        short8 b1 = *(const short8*)(QT + (size_t)(nt * 16 + l15) * 64 + 32 + quad * 8);
        acc[nt] = __builtin_amdgcn_mfma_f32_16x16x32_bf16(s0, b0, acc[nt], 0, 0, 0);
        acc[nt] = __builtin_amdgcn_mfma_f32_16x16x32_bf16(s1, b1, acc[nt], 0, 0, 0);
    }
#pragma unroll
    for (int r = 0; r < 4; ++r) {
        float s = 0.f;
#pragma unroll
        for (int nt = 0; nt < 4; ++nt) s += tanhf(acc[nt][r]) * ratf[nt * 16 + l15];
        s = red16(s);
        if (l15 == 0) Eo[row0 + quad * 4 + r] = s;
    }
}

// --------- attention combine: softmax over window, h = mean(a*hlog) -----
template <typename T>
__global__ __launch_bounds__(256) void k_att_h(const float* __restrict__ Eb,
                                               const float* __restrict__ Lt,
                                               const T* __restrict__ hid,
                                               bf16* __restrict__ Hb, int N, int win, const int* flag) {
    if (skip<T>(flag)) return;
    int wid = threadIdx.x >> 6, lane = threadIdx.x & 63;
    int i = blockIdx.x * 4 + wid;
    if (i >= N) return;
    float hl[8], ev[8];
    float m = -1e30f;
    for (int w = 0; w < win; ++w) {
        float p = cv(hid[((size_t)w * N + i) * 64 + lane]);
        hl[w] = Lt[(size_t)w * N + i] * p;
        ev[w] = Eb[(size_t)w * N + i];
        m = fmaxf(m, ev[w]);
    }
    float s = 0.f;
    for (int w = 0; w < win; ++w) { ev[w] = expf(ev[w] - m); s += ev[w]; }
    float h = 0.f;
    for (int w = 0; w < win; ++w) h += ev[w] * hl[w];
    ((short*)Hb)[(size_t)i * 64 + lane] = f2b(h / (s * (float)win));
}

// --------- initial linear + expmap0/proj + concat hidden + proj128 ------
template <typename T>
__global__ __launch_bounds__(256) void k_lin0(const T* __restrict__ feat, const short* __restrict__ Wl,
                                              const float* __restrict__ blf, const T* __restrict__ hid,
                                              int win, float* __restrict__ xnorm,
                                              bf16* __restrict__ outA, int N, const int* flag) {
    if (skip<T>(flag)) return;
    int wid = threadIdx.x >> 6, lane = threadIdx.x & 63;
    int row0 = blockIdx.x * 64 + wid * 16;
    if (row0 >= N) return;
    int l15 = lane & 15, quad = lane >> 4;
    f32x4 acc[4];
#pragma unroll
    for (int nt = 0; nt < 4; ++nt) acc[nt] = (f32x4){0.f, 0.f, 0.f, 0.f};
    const T* Arow = feat + (size_t)(row0 + l15) * 128 + quad * 8;
    for (int k0 = 0; k0 < 128; k0 += 32) {
        short8 a = ld8(Arow + k0);
#pragma unroll
        for (int nt = 0; nt < 4; ++nt) {
            short8 b = *(const short8*)(Wl + (size_t)(nt * 16 + l15) * 128 + k0 + quad * 8);
            acc[nt] = __builtin_amdgcn_mfma_f32_16x16x32_bf16(a, b, acc[nt], 0, 0, 0);
        }
    }
    float bv[4];
#pragma unroll
    for (int nt = 0; nt < 4; ++nt) bv[nt] = blf[nt * 16 + l15];
#pragma unroll
    for (int r = 0; r < 4; ++r) {
        int row = row0 + quad * 4 + r;
        float g[4], u2 = 0.f;
#pragma unroll
        for (int nt = 0; nt < 4; ++nt) { g[nt] = acc[nt][r] + bv[nt]; u2 += g[nt] * g[nt]; }
        u2 = red16(u2);
        float un = fmaxf(sqrtf(u2), MINN);
        float e = tanhf(un), t = e / un;
        float s1 = (e > MAXN) ? MAXN / e : 1.f;
        float x0n = s1 * e;
        float hv[4], h2 = 0.f;
#pragma unroll
        for (int nt = 0; nt < 4; ++nt) {
            hv[nt] = cv(hid[((size_t)(win - 1) * N + row) * 64 + nt * 16 + l15]);
            h2 += hv[nt] * hv[nt];
        }
        h2 = red16(h2);
        float n128 = sqrtf(x0n * x0n + h2);
        float s2 = (n128 > MAXN) ? MAXN / n128 : 1.f;
#pragma unroll
        for (int nt = 0; nt < 4; ++nt) {
            ((short*)outA)[(size_t)row * 128 + nt * 16 + l15] = f2b(s2 * s1 * t * g[nt]);
            ((short*)outA)[(size_t)row * 128 + 64 + nt * 16 + l15] = f2b(s2 * hv[nt]);
        }
        if (l15 == 0) xnorm[row] = fmaxf(fminf(n128, MAXN), MINN);
    }
}

// ------- conv linear: GEMM fused with matvec->proj->madd(hb)->proj->logmap0 ----
// Weights are pre-converted bf16 (dtype-free kernel).
template <int DOUT>
__global__ __launch_bounds__(256) void k_conv_lin(const bf16* __restrict__ in, const short* __restrict__ W,
                                                  const float* __restrict__ hb, const float* __restrict__ y2p,
                                                  const float* __restrict__ xnorm,
                                                  bf16* __restrict__ out, int N) {
    constexpr int NT = DOUT / 16;
    int wid = threadIdx.x >> 6, lane = threadIdx.x & 63;
    int row0 = blockIdx.x * 64 + wid * 16;
    if (row0 >= N) return;
    int l15 = lane & 15, quad = lane >> 4;
    f32x4 acc[NT];
#pragma unroll
    for (int nt = 0; nt < NT; ++nt) acc[nt] = (f32x4){0.f, 0.f, 0.f, 0.f};
    const short* Arow = (const short*)in + (size_t)(row0 + l15) * 128 + quad * 8;
    for (int k0 = 0; k0 < 128; k0 += 32) {
        short8 a = *(const short8*)(Arow + k0);
#pragma unroll
        for (int nt = 0; nt < NT; ++nt) {
            short8 b = *(const short8*)(W + (size_t)(nt * 16 + l15) * 128 + k0 + quad * 8);
            acc[nt] = __builtin_amdgcn_mfma_f32_16x16x32_bf16(a, b, acc[nt], 0, 0, 0);
        }
    }
    float y2 = y2p[0];
    float hbv[NT];
#pragma unroll
    for (int nt = 0; nt < NT; ++nt) hbv[nt] = hb[nt * 16 + l15];
#pragma unroll
    for (int r = 0; r < 4; ++r) {
        int row = row0 + quad * 4 + r;
        float mx[NT], m2 = 0.f;
#pragma unroll
        for (int nt = 0; nt < NT; ++nt) { mx[nt] = acc[nt][r]; m2 += mx[nt] * mx[nt]; }
        m2 = red16(m2);
        float mxn = fmaxf(sqrtf(m2), MINN);
        float xn = xnorm[row];
        float at = artanh_(xn);
        float f = (m2 == 0.f) ? 0.f : tanhf(mxn / xn * at) / mxn;
        float rn = f * mxn;
        float s1 = (rn > MAXN) ? MAXN / rn : 1.f;
        float a_ = s1 * f, mvn = s1 * rn;
        float x2 = mvn * mvn;
        float xy = 0.f;
#pragma unroll
        for (int nt = 0; nt < NT; ++nt) xy += (a_ * mx[nt]) * hbv[nt];
        xy = red16(xy);
        float co = 1.f + 2.f * xy + y2, cx = 1.f - x2;
        float den = fmaxf(1.f + 2.f * xy + x2 * y2, MINN);
        float o[NT], on2 = 0.f;
#pragma unroll
        for (int nt = 0; nt < NT; ++nt) { o[nt] = (co * a_ * mx[nt] + cx * hbv[nt]) / den; on2 += o[nt] * o[nt]; }
        on2 = red16(on2);
        float on = sqrtf(on2);
        float s3 = (on > MAXN) ? MAXN / on : 1.f;
        float hn = fmaxf(s3 * on, MINN);
        float lt = artanh_(hn) / hn;
#pragma unroll
        for (int nt = 0; nt < NT; ++nt)
            ((short*)out)[(size_t)row * 128 + nt * 16 + l15] = f2b(lt * s3 * o[nt]);
    }
}

// --------- agg (conv1, D=128): 4 nodes/wave, 16 lanes/node, dwordx4 -------
__global__ __launch_bounds__(256) void k_agg2(const bf16* __restrict__ xt, const int* __restrict__ rowptr,
                                              const int2* __restrict__ edge,
                                              const float* __restrict__ dis,
                                              bf16* __restrict__ out, float* __restrict__ xnorm, int N) {
    int wid = threadIdx.x >> 6, lane = threadIdx.x & 63;
    int g = lane >> 4, l15 = lane & 15;
    int i = blockIdx.x * 16 + wid * 4 + g;
    bool act = (i < N);
    int ii = act ? i : (N - 1);
    const u32x4* xq = (const u32x4*)xt;            // 16 u32x4 per 128-feat row
    float di = dis[ii];
    float w0 = di * di;
    u32x4 d0 = xq[(size_t)ii * 16 + l15];
    float a[8];
#pragma unroll
    for (int k = 0; k < 4; ++k) { a[2 * k] = w0 * lo16f(d0[k]); a[2 * k + 1] = w0 * hi16f(d0[k]); }
    int e0 = rowptr[ii], e1 = act ? rowptr[ii + 1] : e0;
    for (int j = e0; j < e1; ++j) {
        int2 e = edge[j];
        float w = __int_as_float(e.y);
        u32x4 d = xq[(size_t)e.x * 16 + l15];
#pragma unroll
        for (int k = 0; k < 4; ++k) { a[2 * k] += w * lo16f(d[k]); a[2 * k + 1] += w * hi16f(d[k]); }
    }
    float sq = 0.f;
#pragma unroll
    for (int k = 0; k < 8; ++k) sq += a[k] * a[k];
    float an = fmaxf(sqrtf(red16(sq)), MINN);
    float e1t = tanhf(an), t1 = e1t / an;
    float s1 = (e1t > MAXN) ? MAXN / e1t : 1.f;
    float hn = fmaxf(s1 * e1t, MINN);
    float lt = artanh_(hn) / hn;
    float sht = s1 * t1 * lt;
    float v[8], v2 = 0.f;
#pragma unroll
    for (int k = 0; k < 8; ++k) {
        float t = sht * a[k];
        t = (t >= 0.f) ? t : 0.01f * t;
        v[k] = t; v2 += t * t;
    }
    float tn = fmaxf(sqrtf(red16(v2)), MINN);
    float e2 = tanhf(tn), t2 = e2 / tn;
    float s2 = (e2 > MAXN) ? MAXN / e2 : 1.f;
    float sc = s2 * t2;
    if (act) {
        u32x4 o;
#pragma unroll
        for (int k = 0; k < 4; ++k) o[k] = pk2(sc * v[2 * k], sc * v[2 * k + 1]);
        ((u32x4*)out)[(size_t)i * 16 + l15] = o;
        if (l15 == 0) xnorm[i] = fmaxf(fminf(e2, MAXN), MINN);
    }
}

// --------- agg (conv2, D=64) + FINAL logmap0: 8 nodes/wave, 8 lanes/node --
__global__ __launch_bounds__(256) void k_agg1f(const bf16* __restrict__ xt, const int* __restrict__ rowptr,
                                               const int2* __restrict__ edge,
                                               const float* __restrict__ dis,
                                               bf16* __restrict__ out, const bf16* __restrict__ Hb, int N) {
    int wid = threadIdx.x >> 6, lane = threadIdx.x & 63;
    int g = lane >> 3, l7 = lane & 7;
    int i = blockIdx.x * 32 + wid * 8 + g;
    bool act = (i < N);
    int ii = act ? i : (N - 1);
    const u32x4* xq = (const u32x4*)xt;            // row stride 16 u32x4; feats = first 8
    float di = dis[ii];
    float w0 = di * di;
    u32x4 d0 = xq[(size_t)ii * 16 + l7];
    float a[8];
#pragma unroll
    for (int k = 0; k < 4; ++k) { a[2 * k] = w0 * lo16f(d0[k]); a[2 * k + 1] = w0 * hi16f(d0[k]); }
    int e0 = rowptr[ii], e1 = act ? rowptr[ii + 1] : e0;
    for (int j = e0; j < e1; ++j) {
        int2 e = edge[j];
        float w = __int_as_float(e.y);
        u32x4 d = xq[(size_t)e.x * 16 + l7];
#pragma unroll
        for (int k = 0; k < 4; ++k) { a[2 * k] += w * lo16f(d[k]); a[2 * k + 1] += w * hi16f(d[k]); }
    }
    float sq = 0.f;
#pragma unroll
    for (int k = 0; k < 8; ++k) sq += a[k] * a[k];
    float an = fmaxf(sqrtf(red8(sq)), MINN);
    float e1t = tanhf(an), t1 = e1t / an;
    float s1 = (e1t > MAXN) ? MAXN / e1t : 1.f;
    float hn = fmaxf(s1 * e1t, MINN);
    float lt = artanh_(hn) / hn;
    float sht = s1 * t1 * lt;
    float v[8], v2 = 0.f;
#pragma unroll
    for (int k = 0; k < 8; ++k) {
        float t = sht * a[k];
        t = (t >= 0.f) ? t : 0.01f * t;
        v[k] = t; v2 += t * t;
    }
    float tn = fmaxf(sqrtf(red8(v2)), MINN);
    float e2 = tanhf(tn), t2 = e2 / tn;
    float s2 = (e2 > MAXN) ? MAXN / e2 : 1.f;
    float sc = s2 * t2;
    float xnf = fmaxf(fminf(s2 * e2, MAXN), MINN);
    float lt2 = artanh_(xnf) / xnf;
    sc *= lt2;
    if (act) {
        u32x4 o;
#pragma unroll
        for (int k = 0; k < 4; ++k) o[k] = pk2(sc * v[2 * k], sc * v[2 * k + 1]);
        u32x4* od = (u32x4*)out;
        od[(size_t)i * 16 + l7] = o;
        od[(size_t)i * 16 + 8 + l7] = ((const u32x4*)Hb)[(size_t)i * 8 + l7];
    }
}

// --------- GRU fused + expmap0/proj -> out (templated on OUT dtype) -----
template <typename OT>
__global__ __launch_bounds__(256) void k_gru_f(const bf16* __restrict__ cat, const short* __restrict__ Wc,
                                               const float* __restrict__ bs, const bf16* __restrict__ Hb,
                                               OT* __restrict__ out, int N, const int* flag) {
    if (skip<OT>(flag)) return;
    int wid = threadIdx.x >> 6, lane = threadIdx.x & 63;
    int row0 = blockIdx.x * 64 + wid * 16;
    if (row0 >= N) return;
    int l15 = lane & 15, quad = lane >> 4;
    f32x4 acc[16];
#pragma unroll
    for (int nt = 0; nt < 16; ++nt) acc[nt] = (f32x4){0.f, 0.f, 0.f, 0.f};
    const short* Arow = (const short*)cat + (size_t)(row0 + l15) * 128 + quad * 8;
    for (int k0 = 0; k0 < 128; k0 += 32) {
        short8 a = *(const short8*)(Arow + k0);
#pragma unroll
        for (int nt = 0; nt < 16; ++nt) {
            short8 b = *(const short8*)(Wc + (size_t)(nt * 16 + l15) * 128 + k0 + quad * 8);
            acc[nt] = __builtin_amdgcn_mfma_f32_16x16x32_bf16(a, b, acc[nt], 0, 0, 0);
        }
    }
#pragma unroll
    for (int r = 0; r < 4; ++r) {
        int row = row0 + quad * 4 + r;
        float zv[4], z2 = 0.f;
#pragma unroll
        for (int nt = 0; nt < 4; ++nt) {
            int c = nt * 16 + l15;
            float gr = acc[nt][r] + bs[c];
            float gz = acc[nt + 4][r] + bs[c + 64];
            float gn = acc[nt + 8][r] + bs[c + 128];
            float hn = acc[nt + 12][r] + bs[c + 192];
            float hv = b2f(((const short*)Hb)[(size_t)row * 64 + c]);
            float rr = sigmoidf_(gr), zz = sigmoidf_(gz);
            float nn = tanhf(gn + (rr - 1.f) * hn);
            zv[nt] = (1.f - zz) * nn + zz * hv;
            z2 += zv[nt] * zv[nt];
        }
        z2 = red16(z2);
        float un = fmaxf(sqrtf(z2), MINN);
        float e = tanhf(un), t = e / un;
        float s = (e > MAXN) ? MAXN / e : 1.f;
#pragma unroll
        for (int nt = 0; nt < 4; ++nt)
            st(&out[(size_t)row * 64 + nt * 16 + l15], s * t * zv[nt]);
    }
}

extern "C" void kernel_launch(void* const* d_in, const int* in_sizes, int n_in,
                              void* d_out, int out_size, void* d_ws, size_t ws_size,
                              hipStream_t stream) {
    const int E = in_sizes[0] / 2;
    const int N = in_sizes[1] / 128;
    int win = in_sizes[14] / (N * 64); if (win > 8) win = 8;

    char* wp = (char*)d_ws;
    auto alloc = [&](size_t bytes) -> void* {
        void* p = (void*)wp;
        wp += (bytes + 255) & ~(size_t)255;
        return p;
    };
    bf16* bufA = (bf16*)alloc((size_t)N * 128 * 2);
    bf16* bufB = (bf16*)alloc((size_t)N * 128 * 2);
    bf16* Hbf  = (bf16*)alloc((size_t)N * 64 * 2);
    float* Ebuf = (float*)alloc((size_t)win * N * 4);
    float* Ltb  = (float*)alloc((size_t)win * N * 4);
    float* xnorm = (float*)alloc((size_t)N * 4);
    int* cnt = (int*)alloc((size_t)N * 4);
    int* fillc = (int*)alloc((size_t)N * 4);
    int* rowptr = (int*)alloc((size_t)(N + 1) * 4);
    float* dis = (float*)alloc((size_t)N * 4);
    int2* edge = (int2*)alloc((size_t)E * 8);
    int* bsum = (int*)alloc((size_t)1025 * 4);
    float* hb1 = (float*)alloc(128 * 4);
    float* y2a = (float*)alloc(256);
    float* hb2 = (float*)alloc(64 * 4);
    float* y2b = (float*)alloc(256);
    float* blf = (float*)alloc(64 * 4);
    float* bs256 = (float*)alloc(256 * 4);
    float* ratf = (float*)alloc(64 * 4);
    short* QT = (short*)alloc(4096 * 2);
    short* Wc = (short*)alloc((size_t)256 * 128 * 2);
    short* Wlb = (short*)alloc((size_t)8192 * 2);
    short* W1b = (short*)alloc((size_t)16384 * 2);
    short* W2b = (short*)alloc((size_t)8192 * 2);
    int* flag = (int*)alloc(256);
    (void)ws_size; (void)out_size; (void)n_in;

    const int* ei = (const int*)d_in[0];

    k_detect<<<1, 256, 0, stream>>>(d_in[14], flag);

    // prep (both dtype variants; non-matching exits immediately)
#define P(T) (const T*)d_in
    k_prep<short><<<1, 256, 0, stream>>>(P(short)[5], P(short)[7], P(short)[3], P(short)[12], P(short)[13],
                                         P(short)[8], P(short)[9], P(short)[10], P(short)[11],
                                         hb1, y2a, hb2, y2b, blf, bs256, ratf, QT, Wc, flag);
    k_prep<float><<<1, 256, 0, stream>>>(P(float)[5], P(float)[7], P(float)[3], P(float)[12], P(float)[13],
                                         P(float)[8], P(float)[9], P(float)[10], P(float)[11],
                                         hb1, y2a, hb2, y2b, blf, bs256, ratf, QT, Wc, flag);
    // weight pre-conversion to bf16 (removes per-wave f32->bf16 in GEMMs)
    k_wcvt<short><<<128, 256, 0, stream>>>(P(short)[2], P(short)[4], P(short)[6], Wlb, W1b, W2b, flag);
    k_wcvt<float><<<128, 256, 0, stream>>>(P(float)[2], P(float)[4], P(float)[6], Wlb, W1b, W2b, flag);
    // CSR build (dtype-free)
    k_zero<<<(N + 255) / 256, 256, 0, stream>>>(cnt, fillc, N);
    k_count<<<(E + 255) / 256, 256, 0, stream>>>(ei, E, cnt);
    {
        int nb = (N + SC_CHUNK - 1) / SC_CHUNK;   // <=1024 for N<=2M
        k_scan_bsum<<<nb, 256, 0, stream>>>(cnt, N, bsum);
        k_scan_bpre<<<1, 1024, 0, stream>>>(bsum, nb);
        k_scan_write<<<nb, 256, 0, stream>>>(cnt, rowptr, N, bsum, nb);
    }
    k_dis<<<(N + 255) / 256, 256, 0, stream>>>(cnt, dis, N);
    k_fill<<<(E + 255) / 256, 256, 0, stream>>>(ei, ei + E, E, rowptr, fillc, edge, dis);
    // HTA window attention
    int rowsHL = win * N;
    k_att_e<short><<<(rowsHL + 63) / 64, 256, 0, stream>>>(P(short)[14], QT, ratf, Ebuf, Ltb, rowsHL, flag);
    k_att_e<float><<<(rowsHL + 63) / 64, 256, 0, stream>>>(P(float)[14], QT, ratf, Ebuf, Ltb, rowsHL, flag);
    k_att_h<short><<<(N + 3) / 4, 256, 0, stream>>>(Ebuf, Ltb, P(short)[14], Hbf, N, win, flag);
    k_att_h<float><<<(N + 3) / 4, 256, 0, stream>>>(Ebuf, Ltb, P(float)[14], Hbf, N, win, flag);
    // initial linear + toHyperX + concat
    k_lin0<short><<<(N + 63) / 64, 256, 0, stream>>>(P(short)[1], Wlb, blf, P(short)[14], win, xnorm, bufA, N, flag);
    k_lin0<float><<<(N + 63) / 64, 256, 0, stream>>>(P(float)[1], Wlb, blf, P(float)[14], win, xnorm, bufA, N, flag);
    // conv1
    k_conv_lin<128><<<(N + 63) / 64, 256, 0, stream>>>(bufA, W1b, hb1, y2a, xnorm, bufA, N);
    k_agg2<<<(N + 15) / 16, 256, 0, stream>>>(bufA, rowptr, edge, dis, bufB, xnorm, N);
    // conv2
    k_conv_lin<64><<<(N + 63) / 64, 256, 0, stream>>>(bufB, W2b, hb2, y2b, xnorm, bufB, N);
    k_agg1f<<<(N + 31) / 32, 256, 0, stream>>>(bufB, rowptr, edge, dis, bufA, Hbf, N);
    // GRU fused + toHyperX -> out (output dtype = detected input dtype)
    k_gru_f<short><<<(N + 63) / 64, 256, 0, stream>>>(bufA, Wc, bs256, Hbf, (short*)d_out, N, flag);
    k_gru_f<float><<<(N + 63) / 64, 256, 0, stream>>>(bufA, Wc, bs256, Hbf, (float*)d_out, N, flag);
#undef P
}